// Round 9
// baseline (702.035 us; speedup 1.0000x reference)
//
#include <hip/hip_runtime.h>

typedef unsigned short u16;
typedef __attribute__((ext_vector_type(8))) short short8;     // 8 bf16 (4 VGPRs)
typedef __attribute__((ext_vector_type(4))) float floatx4;    // 4 fp32 acc

#define B_ 4
#define T_ 2048

__device__ __forceinline__ u16 f2bf(float f) {
  unsigned int x = __float_as_uint(f);
  return (u16)((x + 0x7FFFu + ((x >> 16) & 1u)) >> 16);
}
__device__ __forceinline__ float bf2f(u16 u) {
  union { unsigned int i; float f; } v; v.i = ((unsigned int)u) << 16; return v.f;
}

// lgkm-only barrier: all cross-wave hazards in chain_kernel are LDS.
__device__ __forceinline__ void barrier_lgkm() {
  asm volatile("s_waitcnt lgkmcnt(0)\n\ts_barrier" ::: "memory");
}

// ---------------------------------------------------------------------------
// x fp32 -> bf16 (full tensor). grid (B_*T_), 256 thr x 4 elems.
// ---------------------------------------------------------------------------
__global__ __launch_bounds__(256) void xconv_kernel(const float* __restrict__ x,
                                                    u16* __restrict__ Xbf) {
  size_t idx = ((size_t)blockIdx.x * 256 + threadIdx.x) * 4;
  float4 v = *reinterpret_cast<const float4*>(&x[idx]);
  ushort4 o;
  o.x = f2bf(v.x); o.y = f2bf(v.y); o.z = f2bf(v.z); o.w = f2bf(v.w);
  *reinterpret_cast<ushort4*>(&Xbf[idx]) = o;
}

// ---------------------------------------------------------------------------
// Weight transpose+convert: T[n][k] = bf16(W[k][n]). grid (16,16,4).
// ---------------------------------------------------------------------------
__global__ __launch_bounds__(256) void wtrans_kernel(
    const float* __restrict__ W0, const float* __restrict__ W1,
    const float* __restrict__ W2, const float* __restrict__ W3,
    u16* __restrict__ T0, u16* __restrict__ T1,
    u16* __restrict__ T2, u16* __restrict__ T3)
{
  const int z = blockIdx.z;
  const float* W = (z == 0) ? W0 : (z == 1) ? W1 : (z == 2) ? W2 : W3;
  u16* T = (z == 0) ? T0 : (z == 1) ? T1 : (z == 2) ? T2 : T3;
  const int k0 = blockIdx.x * 64, n0 = blockIdx.y * 64;
  const int tid = threadIdx.x;
  __shared__ float Tile[64][65];
#pragma unroll
  for (int i = 0; i < 4; ++i) {
    int lin = tid + i * 256;
    int r = lin >> 4, c4 = (lin & 15) * 4;
    *reinterpret_cast<float4*>(&Tile[r][c4]) =
        *reinterpret_cast<const float4*>(&W[(size_t)(k0 + r) * 1024 + n0 + c4]);
  }
  __syncthreads();
#pragma unroll
  for (int i = 0; i < 4; ++i) {
    int lin = tid + i * 256;
    int r = lin >> 4, c4 = (lin & 15) * 4;
    ushort4 o;
    o.x = f2bf(Tile[c4 + 0][r]); o.y = f2bf(Tile[c4 + 1][r]);
    o.z = f2bf(Tile[c4 + 2][r]); o.w = f2bf(Tile[c4 + 3][r]);
    *reinterpret_cast<ushort4*>(&T[(size_t)(n0 + r) * 1024 + k0 + c4]) = o;
  }
}

// ---------------------------------------------------------------------------
// MFMA GEMM for QKV. 128x128 tile, 4 waves (2x2), 4x4 of 16x16x32, BK=32.
// grid (rows/128, 8, 3).
// ---------------------------------------------------------------------------
__global__ __launch_bounds__(256) void mgemm_qkv(
    const u16* __restrict__ Xbf,
    const u16* __restrict__ WqT, const u16* __restrict__ WkT, const u16* __restrict__ WvT,
    u16* __restrict__ Qbf, u16* __restrict__ Kbf, u16* __restrict__ Vbf,
    int tg, int lsh)
{
  const int z = blockIdx.z;
  const u16* BT = (z == 0) ? WqT : ((z == 1) ? WkT : WvT);
  u16* O = (z == 0) ? Qbf : ((z == 1) ? Kbf : Vbf);
  const float scale = (z == 0) ? 0.03125f : 1.0f;
  const int r0 = blockIdx.x * 128, c0 = blockIdx.y * 128;
  const int tid = threadIdx.x;
  const int lane = tid & 63, wave = tid >> 6;
  const int quad = lane >> 4, l16 = lane & 15;
  const int wr = (wave >> 1) * 64, wc = (wave & 1) * 64;

  __shared__ u16 As[128][40];
  __shared__ u16 Bs[128][40];

  const int ar = tid >> 1, ac = (tid & 1) * 16;
  const int lr = r0 + ar;
  const int agrow = ((lr >> lsh) << 11) + tg + (lr & ((1 << lsh) - 1));
  const u16* aptr = &Xbf[(size_t)agrow * 1024 + ac];
  const u16* bptr = &BT[(size_t)(c0 + ar) * 1024 + ac];

  floatx4 acc[4][4] = {};
  for (int k0 = 0; k0 < 1024; k0 += 32) {
    float4 av0 = *reinterpret_cast<const float4*>(aptr + k0);
    float4 av1 = *reinterpret_cast<const float4*>(aptr + k0 + 8);
    float4 bv0 = *reinterpret_cast<const float4*>(bptr + k0);
    float4 bv1 = *reinterpret_cast<const float4*>(bptr + k0 + 8);
    __syncthreads();
    *reinterpret_cast<float4*>(&As[ar][ac]) = av0;
    *reinterpret_cast<float4*>(&As[ar][ac + 8]) = av1;
    *reinterpret_cast<float4*>(&Bs[ar][ac]) = bv0;
    *reinterpret_cast<float4*>(&Bs[ar][ac + 8]) = bv1;
    __syncthreads();
    short8 afr[4], bfr[4];
#pragma unroll
    for (int i = 0; i < 4; ++i) {
      afr[i] = *reinterpret_cast<const short8*>(&As[wr + i * 16 + l16][quad * 8]);
      bfr[i] = *reinterpret_cast<const short8*>(&Bs[wc + i * 16 + l16][quad * 8]);
    }
#pragma unroll
    for (int mi = 0; mi < 4; ++mi)
#pragma unroll
      for (int ni = 0; ni < 4; ++ni)
        acc[mi][ni] = __builtin_amdgcn_mfma_f32_16x16x32_bf16(afr[mi], bfr[ni], acc[mi][ni], 0, 0, 0);
  }
#pragma unroll
  for (int mi = 0; mi < 4; ++mi)
#pragma unroll
    for (int reg = 0; reg < 4; ++reg) {
      int row = r0 + wr + mi * 16 + quad * 4 + reg;
#pragma unroll
      for (int ni = 0; ni < 4; ++ni) {
        int col = c0 + wc + ni * 16 + l16;
        O[(size_t)row * 1024 + col] = f2bf(acc[mi][ni][reg] * scale);
      }
    }
}

// ---------------------------------------------------------------------------
// MFMA GEMM out-proj: fp32 out. grid (rows/128, 8)
// ---------------------------------------------------------------------------
__global__ __launch_bounds__(256) void mgemm_out(
    const u16* __restrict__ Obf, const u16* __restrict__ WoT,
    float* __restrict__ out, int tg, int lsh)
{
  const int r0 = blockIdx.x * 128, c0 = blockIdx.y * 128;
  const int tid = threadIdx.x;
  const int lane = tid & 63, wave = tid >> 6;
  const int quad = lane >> 4, l16 = lane & 15;
  const int wr = (wave >> 1) * 64, wc = (wave & 1) * 64;

  __shared__ u16 As[128][40];
  __shared__ u16 Bs[128][40];

  const int ar = tid >> 1, ac = (tid & 1) * 16;
  const u16* aptr = &Obf[(size_t)(r0 + ar) * 1024 + ac];
  const u16* bptr = &WoT[(size_t)(c0 + ar) * 1024 + ac];

  floatx4 acc[4][4] = {};
  for (int k0 = 0; k0 < 1024; k0 += 32) {
    float4 av0 = *reinterpret_cast<const float4*>(aptr + k0);
    float4 av1 = *reinterpret_cast<const float4*>(aptr + k0 + 8);
    float4 bv0 = *reinterpret_cast<const float4*>(bptr + k0);
    float4 bv1 = *reinterpret_cast<const float4*>(bptr + k0 + 8);
    __syncthreads();
    *reinterpret_cast<float4*>(&As[ar][ac]) = av0;
    *reinterpret_cast<float4*>(&As[ar][ac + 8]) = av1;
    *reinterpret_cast<float4*>(&Bs[ar][ac]) = bv0;
    *reinterpret_cast<float4*>(&Bs[ar][ac + 8]) = bv1;
    __syncthreads();
    short8 afr[4], bfr[4];
#pragma unroll
    for (int i = 0; i < 4; ++i) {
      afr[i] = *reinterpret_cast<const short8*>(&As[wr + i * 16 + l16][quad * 8]);
      bfr[i] = *reinterpret_cast<const short8*>(&Bs[wc + i * 16 + l16][quad * 8]);
    }
#pragma unroll
    for (int mi = 0; mi < 4; ++mi)
#pragma unroll
      for (int ni = 0; ni < 4; ++ni)
        acc[mi][ni] = __builtin_amdgcn_mfma_f32_16x16x32_bf16(afr[mi], bfr[ni], acc[mi][ni], 0, 0, 0);
  }
#pragma unroll
  for (int mi = 0; mi < 4; ++mi)
#pragma unroll
    for (int reg = 0; reg < 4; ++reg) {
      int lr = r0 + wr + mi * 16 + quad * 4 + reg;
      int grow = ((lr >> lsh) << 11) + tg + (lr & ((1 << lsh) - 1));
#pragma unroll
      for (int ni = 0; ni < 4; ++ni) {
        int col = c0 + wc + ni * 16 + l16;
        out[(size_t)grow * 1024 + col] = acc[mi][ni][reg];
      }
    }
}

// ---------------------------------------------------------------------------
// Row-normalize Kbf in place (bf16, fp32 math). grid (rows).
// ---------------------------------------------------------------------------
__global__ __launch_bounds__(256) void knorm_kernel(u16* __restrict__ Kbf) {
  const int row = blockIdx.x;
  const int tid = threadIdx.x;
  ushort4 v4 = *reinterpret_cast<const ushort4*>(&Kbf[(size_t)row * 1024 + tid * 4]);
  float a = bf2f(v4.x), b = bf2f(v4.y), c = bf2f(v4.z), d = bf2f(v4.w);
  float ss = a * a + b * b + c * c + d * d;
#pragma unroll
  for (int off = 32; off > 0; off >>= 1) ss += __shfl_down(ss, off);
  __shared__ float wsum[4];
  if ((tid & 63) == 0) wsum[tid >> 6] = ss;
  __syncthreads();
  float tot = wsum[0] + wsum[1] + wsum[2] + wsum[3];
  float inv = 1.0f / fmaxf(sqrtf(tot), 1e-12f);
  ushort4 o;
  o.x = f2bf(a * inv); o.y = f2bf(b * inv); o.z = f2bf(c * inv); o.w = f2bf(d * inv);
  *reinterpret_cast<ushort4*>(&Kbf[(size_t)row * 1024 + tid * 4]) = o;
}

// ---------------------------------------------------------------------------
// Transpose Kbf -> KT[b][d][t_local] (bf16). grid (tgs/64, 16, B_), 256 thr.
// ---------------------------------------------------------------------------
__global__ __launch_bounds__(256) void ktrans_kernel(const u16* __restrict__ Kbf,
                                                     u16* __restrict__ KT,
                                                     int tgs) {
  const int t0 = blockIdx.x * 64;
  const int d0 = blockIdx.y * 64;
  const int b = blockIdx.z;
  const int tid = threadIdx.x;
  __shared__ u16 Tile[64][68];
#pragma unroll
  for (int i = 0; i < 4; ++i) {
    int lin = tid + i * 256;
    int r = lin >> 4, c4 = (lin & 15) * 4;
    *reinterpret_cast<ushort4*>(&Tile[r][c4]) =
        *reinterpret_cast<const ushort4*>(&Kbf[(size_t)(b * tgs + t0 + r) * 1024 + d0 + c4]);
  }
  __syncthreads();
#pragma unroll
  for (int i = 0; i < 4; ++i) {
    int lin = tid + i * 256;
    int r = lin >> 4, c4 = (lin & 15) * 4;
    ushort4 o;
    o.x = Tile[c4 + 0][r]; o.y = Tile[c4 + 1][r];
    o.z = Tile[c4 + 2][r]; o.w = Tile[c4 + 3][r];
    *reinterpret_cast<ushort4*>(&KT[((size_t)b * 1024 + d0 + r) * tgs + t0 + c4]) = o;
  }
}

// ---------------------------------------------------------------------------
// Per (64-chunk, batch): P=tril(QK^T), A=stril(KK^T), W=(I+A)^{-1}; also
// W^T (for wcomp) and cross-chunk couplings M=K_c K_{c-1}^T, N=Q_c K_{c-1}^T
// (zeros at c==0). grid (cpg64, B_), 256 threads. (v4 variant + WbT.)
// ---------------------------------------------------------------------------
__global__ __launch_bounds__(256) void attn_winv_kernel(
    const u16* __restrict__ Qbf, const u16* __restrict__ Kbf,
    u16* __restrict__ Pb, u16* __restrict__ Wb, u16* __restrict__ WbT,
    u16* __restrict__ Mb, u16* __restrict__ Nb, int tgs)
{
  const int cc = blockIdx.x;
  const int b = blockIdx.y;
  const int base = b * tgs + cc * 64;
  const int basep = base - (cc > 0 ? 64 : 0);
  const int tid = threadIdx.x;
  const int lane = tid & 63;
  const int wave = tid >> 6;
  const int quad = lane >> 4, l16 = lane & 15;
  const int m0 = wave * 16;

  __shared__ float Asm[64][64];
  __shared__ float Wsm[64][65];

  floatx4 accA[4] = {};
  floatx4 accP[4] = {};
  floatx4 accM[4] = {};
  floatx4 accN[4] = {};
  const u16* arowK = &Kbf[(size_t)(base + m0 + l16) * 1024];
  const u16* arowQ = &Qbf[(size_t)(base + m0 + l16) * 1024];
#pragma unroll 2
  for (int kk = 0; kk < 32; ++kk) {
    short8 aK = *reinterpret_cast<const short8*>(&arowK[kk * 32 + quad * 8]);
    short8 aQ = *reinterpret_cast<const short8*>(&arowQ[kk * 32 + quad * 8]);
#pragma unroll
    for (int nt = 0; nt < 4; ++nt) {
      short8 bK = *reinterpret_cast<const short8*>(
          &Kbf[(size_t)(base + nt * 16 + l16) * 1024 + kk * 32 + quad * 8]);
      accA[nt] = __builtin_amdgcn_mfma_f32_16x16x32_bf16(aK, bK, accA[nt], 0, 0, 0);
      accP[nt] = __builtin_amdgcn_mfma_f32_16x16x32_bf16(aQ, bK, accP[nt], 0, 0, 0);
    }
    if (cc > 0) {
#pragma unroll
      for (int nt = 0; nt < 4; ++nt) {
        short8 bKp = *reinterpret_cast<const short8*>(
            &Kbf[(size_t)(basep + nt * 16 + l16) * 1024 + kk * 32 + quad * 8]);
        accM[nt] = __builtin_amdgcn_mfma_f32_16x16x32_bf16(aK, bKp, accM[nt], 0, 0, 0);
        accN[nt] = __builtin_amdgcn_mfma_f32_16x16x32_bf16(aQ, bKp, accN[nt], 0, 0, 0);
      }
    }
  }
  const size_t pw0 = ((size_t)(cc * B_ + b) * 64) * 64;
#pragma unroll
  for (int nt = 0; nt < 4; ++nt) {
#pragma unroll
    for (int reg = 0; reg < 4; ++reg) {
      int t = m0 + quad * 4 + reg;
      int i = nt * 16 + l16;
      Asm[t][i] = (i < t) ? accA[nt][reg] : 0.0f;
      Pb[pw0 + (size_t)t * 64 + i] = f2bf((i <= t) ? accP[nt][reg] : 0.0f);
      Mb[pw0 + (size_t)t * 64 + i] = f2bf(accM[nt][reg]);   // zeros when cc==0
      Nb[pw0 + (size_t)t * 64 + i] = f2bf(accN[nt][reg]);
    }
  }
  __syncthreads();

  if (tid < 64) {
    const int j = tid;
    for (int t = 0; t < 64; ++t) {
      float s = (t == j) ? 1.0f : 0.0f;
      for (int i = 0; i < t; ++i) s -= Asm[t][i] * Wsm[i][j];
      Wsm[t][j] = s;
    }
    for (int t = 0; t < 64; ++t) {
      u16 w = f2bf(Wsm[t][j]);
      Wb[pw0 + (size_t)t * 64 + j] = w;
      WbT[pw0 + (size_t)j * 64 + t] = w;
    }
  }
}

// ---------------------------------------------------------------------------
// Compose 128-level W/P from 64-level pieces (one block per (chunk128, b)):
//   W128 = [[W1, 0], [-W2*(M*W1), W2]]   (inverse of block-lower-tri I+A128)
//   P128 = [[P1, 0], [N, P2]]
// 256 thr, 4 waves x 16 rows. MFMA convention: mfma(aRow,bRow) = A*B^T.
// ---------------------------------------------------------------------------
__global__ __launch_bounds__(256) void wcomp_kernel(
    const u16* __restrict__ Pb, const u16* __restrict__ Wb,
    const u16* __restrict__ WbT, const u16* __restrict__ Mb,
    const u16* __restrict__ Nb,
    u16* __restrict__ W128, u16* __restrict__ P128)
{
  const int c1 = blockIdx.x;
  const int b = blockIdx.y;
  const int cc1 = 2 * c1, cc2 = 2 * c1 + 1;
  const size_t pw1 = ((size_t)(cc1 * B_ + b)) * 4096;
  const size_t pw2 = ((size_t)(cc2 * B_ + b)) * 4096;
  const size_t pwX = ((size_t)(c1 * B_ + b)) * 16384;
  const int tid = threadIdx.x;
  const int lane = tid & 63, wave = tid >> 6;
  const int quad = lane >> 4, l16 = lane & 15;
  const int m0 = wave * 16;

  __shared__ u16 XT[64][72];   // X^T (bf16), X = M*W1

  // Phase 1: X[m][j] = sum_t M[m][t] W1[t][j] = mfma(M-row m, W1T-row j).
  floatx4 xacc[4] = {};
#pragma unroll
  for (int kk = 0; kk < 2; ++kk) {
    short8 mf = *reinterpret_cast<const short8*>(
        &Mb[pw2 + (size_t)(m0 + l16) * 64 + kk * 32 + quad * 8]);
#pragma unroll
    for (int nt = 0; nt < 4; ++nt) {
      short8 w1tf = *reinterpret_cast<const short8*>(
          &WbT[pw1 + (size_t)(nt * 16 + l16) * 64 + kk * 32 + quad * 8]);
      xacc[nt] = __builtin_amdgcn_mfma_f32_16x16x32_bf16(mf, w1tf, xacc[nt], 0, 0, 0);
    }
  }
#pragma unroll
  for (int nt = 0; nt < 4; ++nt)
#pragma unroll
    for (int reg = 0; reg < 4; ++reg)
      XT[nt * 16 + l16][m0 + quad * 4 + reg] = f2bf(xacc[nt][reg]);

  // Block copies (independent of X): diag blocks + zero + N.
  for (int idx = tid; idx < 4096; idx += 256) {
    int t = idx >> 6, j = idx & 63;
    W128[pwX + (size_t)t * 128 + j]            = Wb[pw1 + (size_t)t * 64 + j];
    W128[pwX + (size_t)t * 128 + 64 + j]       = 0;
    W128[pwX + (size_t)(64 + t) * 128 + 64 + j] = Wb[pw2 + (size_t)t * 64 + j];
    P128[pwX + (size_t)t * 128 + j]            = Pb[pw1 + (size_t)t * 64 + j];
    P128[pwX + (size_t)t * 128 + 64 + j]       = 0;
    P128[pwX + (size_t)(64 + t) * 128 + j]     = Nb[pw2 + (size_t)t * 64 + j];
    P128[pwX + (size_t)(64 + t) * 128 + 64 + j] = Pb[pw2 + (size_t)t * 64 + j];
  }
  __syncthreads();

  // Phase 2: W21[m][j] = -sum_t W2[m][t] X[t][j] = -mfma(W2-row m, XT-row j).
  floatx4 facc[4] = {};
#pragma unroll
  for (int kk = 0; kk < 2; ++kk) {
    short8 w2f = *reinterpret_cast<const short8*>(
        &Wb[pw2 + (size_t)(m0 + l16) * 64 + kk * 32 + quad * 8]);
#pragma unroll
    for (int nt = 0; nt < 4; ++nt) {
      short8 xtf = *reinterpret_cast<const short8*>(&XT[nt * 16 + l16][kk * 32 + quad * 8]);
      facc[nt] = __builtin_amdgcn_mfma_f32_16x16x32_bf16(w2f, xtf, facc[nt], 0, 0, 0);
    }
  }
#pragma unroll
  for (int nt = 0; nt < 4; ++nt)
#pragma unroll
    for (int reg = 0; reg < 4; ++reg)
      W128[pwX + (size_t)(64 + m0 + quad * 4 + reg) * 128 + nt * 16 + l16] =
          f2bf(-facc[nt][reg]);
}

// ---------------------------------------------------------------------------
// Persistent-state MFMA chain, v6: CH=128 (chunk = 128 rows), 256 WGs.
// DIAGNOSIS (v1-v5): per-chunk time (~12us) is a FIXED per-iteration cost --
// v5 doubled per-WG work (2 slices) at +6% time. v6 amortizes it at full
// chip: the A-phase d-contraction (d=1024, 8 iterations) now feeds TWO
// 64-row blocks per wave (B-frags shared, exactly v5's free doubling), and
// chunk count halves (32->16): per-WG A-iterations and barrier phases halve.
// The intra-128 sequencing lives in the composed W128/P128 (wcomp).
// Plain C++ loads (v1-v3 proved load scheduling irrelevant here).
// ---------------------------------------------------------------------------
__global__ __launch_bounds__(512, 2) void chain_kernel(
    const u16* __restrict__ Qbf, const u16* __restrict__ Kbf,
    const u16* __restrict__ KT, const u16* __restrict__ Vbf,
    u16* __restrict__ Obf, const u16* __restrict__ W128, const u16* __restrict__ P128,
    float* __restrict__ Sglob, int lsh, int cpg, int g, int ngrp)
{
  const int wg = blockIdx.x;   // 256 WGs
  // XCD pair {2b,2b+1} hosts batch b (bijective for nwg=256, 8 XCDs).
  const int t8 = wg & 7;
  const int b = t8 >> 1;
  const int sl = ((wg >> 3) << 1) | (t8 & 1);
  const int c0 = sl * 16;
  const int tgs = 1 << lsh;
  const int tid = threadIdx.x;
  const int lane = tid & 63;
  const int wave = tid >> 6;
  const int quad = lane >> 4, l16 = lane & 15;
  const int d0w = wave * 128;
  const bool isK = (wave < 4);
  const int m0 = (isK ? wave : (wave - 4)) * 16;

  __shared__ u16 Sb[16][1048];    // bf16 shadow of S[c 16][d 1024]
  __shared__ u16 rhsT[16][136];   // (V - KS)^T bf16, t-dim 128
  __shared__ u16 uT[16][136];     // u^T bf16

  // fp32 master S: Sreg[nt][reg] <-> S[c=quad*4+reg][d=d0w+nt*16+l16]
  floatx4 Sreg[8];
  if (g == 0) {
#pragma unroll
    for (int nt = 0; nt < 8; ++nt) Sreg[nt] = (floatx4){0.f, 0.f, 0.f, 0.f};
    for (int idx = tid; idx < 16 * 256; idx += 512) {
      int r = idx >> 8, d4 = (idx & 255) * 4;
      ushort4 z4 = {0, 0, 0, 0};
      *reinterpret_cast<ushort4*>(&Sb[r][d4]) = z4;
    }
  } else {
#pragma unroll
    for (int nt = 0; nt < 8; ++nt)
#pragma unroll
      for (int reg = 0; reg < 4; ++reg)
        Sreg[nt][reg] = Sglob[((size_t)b * 1024 + c0 + quad * 4 + reg) * 1024 +
                              d0w + nt * 16 + l16];
    for (int idx = tid; idx < 16 * 1024; idx += 512) {
      int r = idx >> 10, d = idx & 1023;
      Sb[r][d] = f2bf(Sglob[((size_t)b * 1024 + c0 + r) * 1024 + d]);
    }
  }
  __syncthreads();

  const u16* const Abase = isK ? Kbf : Qbf;
  const u16* const WPb   = isK ? W128 : P128;

  for (int cc = 0; cc < cpg; ++cc) {
    const int base = b * tgs + cc * 128;
    const size_t pw = ((size_t)(cc * B_ + b)) * 16384;
    const u16* arowa = Abase + (size_t)(base + m0 + l16) * 1024 + quad * 8;
    const u16* arowb = arowa + (size_t)64 * 1024;

    // ---- phase A: (K or Q) x S^T over d=1024; two 64-row blocks share the
    //      Sb B-frags. 8 iterations x 8 MFMAs (8 independent chains). ----
    floatx4 aa0 = {}, aa1 = {}, aa2 = {}, aa3 = {};
    floatx4 ab0 = {}, ab1 = {}, ab2 = {}, ab3 = {};
#pragma unroll
    for (int kk8 = 0; kk8 < 8; ++kk8) {
      const int kb = kk8 * 4;
      short8 fa0 = *reinterpret_cast<const short8*>(arowa + (kb + 0) * 32);
      short8 fa1 = *reinterpret_cast<const short8*>(arowa + (kb + 1) * 32);
      short8 fa2 = *reinterpret_cast<const short8*>(arowa + (kb + 2) * 32);
      short8 fa3 = *reinterpret_cast<const short8*>(arowa + (kb + 3) * 32);
      short8 fb0 = *reinterpret_cast<const short8*>(arowb + (kb + 0) * 32);
      short8 fb1 = *reinterpret_cast<const short8*>(arowb + (kb + 1) * 32);
      short8 fb2 = *reinterpret_cast<const short8*>(arowb + (kb + 2) * 32);
      short8 fb3 = *reinterpret_cast<const short8*>(arowb + (kb + 3) * 32);
      short8 s0 = *reinterpret_cast<const short8*>(&Sb[l16][(kb + 0) * 32 + quad * 8]);
      short8 s1 = *reinterpret_cast<const short8*>(&Sb[l16][(kb + 1) * 32 + quad * 8]);
      short8 s2 = *reinterpret_cast<const short8*>(&Sb[l16][(kb + 2) * 32 + quad * 8]);
      short8 s3 = *reinterpret_cast<const short8*>(&Sb[l16][(kb + 3) * 32 + quad * 8]);
      aa0 = __builtin_amdgcn_mfma_f32_16x16x32_bf16(fa0, s0, aa0, 0, 0, 0);
      ab0 = __builtin_amdgcn_mfma_f32_16x16x32_bf16(fb0, s0, ab0, 0, 0, 0);
      aa1 = __builtin_amdgcn_mfma_f32_16x16x32_bf16(fa1, s1, aa1, 0, 0, 0);
      ab1 = __builtin_amdgcn_mfma_f32_16x16x32_bf16(fb1, s1, ab1, 0, 0, 0);
      aa2 = __builtin_amdgcn_mfma_f32_16x16x32_bf16(fa2, s2, aa2, 0, 0, 0);
      ab2 = __builtin_amdgcn_mfma_f32_16x16x32_bf16(fb2, s2, ab2, 0, 0, 0);
      aa3 = __builtin_amdgcn_mfma_f32_16x16x32_bf16(fa3, s3, aa3, 0, 0, 0);
      ab3 = __builtin_amdgcn_mfma_f32_16x16x32_bf16(fb3, s3, ab3, 0, 0, 0);
    }
    floatx4 accSa = (aa0 + aa1) + (aa2 + aa3);
    floatx4 accSb = (ab0 + ab1) + (ab2 + ab3);

    // ---- rhs = V - KS (K-waves), both row-blocks ----
    if (isK) {
#pragma unroll
      for (int reg = 0; reg < 4; ++reg) {
        int ra = base + m0 + quad * 4 + reg;
        rhsT[l16][m0 + quad * 4 + reg] =
            f2bf(bf2f(Vbf[(size_t)ra * 1024 + c0 + l16]) - accSa[reg]);
        rhsT[l16][64 + m0 + quad * 4 + reg] =
            f2bf(bf2f(Vbf[(size_t)(ra + 64) * 1024 + c0 + l16]) - accSb[reg]);
      }
    }
    barrier_lgkm();

    // ---- u = W128 * rhs (K-waves); contraction over t'=128 ----
    if (isK) {
      const u16* wra = WPb + pw + (size_t)(m0 + l16) * 128 + quad * 8;
      const u16* wrb = wra + (size_t)64 * 128;
      floatx4 ua = {}, ub = {};
#pragma unroll
      for (int f = 0; f < 4; ++f) {
        short8 br = *reinterpret_cast<const short8*>(&rhsT[l16][f * 32 + quad * 8]);
        short8 wa = *reinterpret_cast<const short8*>(wra + f * 32);
        short8 wb = *reinterpret_cast<const short8*>(wrb + f * 32);
        ua = __builtin_amdgcn_mfma_f32_16x16x32_bf16(wa, br, ua, 0, 0, 0);
        ub = __builtin_amdgcn_mfma_f32_16x16x32_bf16(wb, br, ub, 0, 0, 0);
      }
#pragma unroll
      for (int reg = 0; reg < 4; ++reg) {
        uT[l16][m0 + quad * 4 + reg] = f2bf(ua[reg]);
        uT[l16][64 + m0 + quad * 4 + reg] = f2bf(ub[reg]);
      }
    }
    barrier_lgkm();

    // ---- o = QS + P128*u (Q-waves), both row-blocks ----
    if (!isK) {
      const u16* pra = WPb + pw + (size_t)(m0 + l16) * 128 + quad * 8;
      const u16* prb = pra + (size_t)64 * 128;
      floatx4 oa = accSa, ob = accSb;
#pragma unroll
      for (int f = 0; f < 4; ++f) {
        short8 bu = *reinterpret_cast<const short8*>(&uT[l16][f * 32 + quad * 8]);
        short8 pa = *reinterpret_cast<const short8*>(pra + f * 32);
        short8 pb = *reinterpret_cast<const short8*>(prb + f * 32);
        oa = __builtin_amdgcn_mfma_f32_16x16x32_bf16(pa, bu, oa, 0, 0, 0);
        ob = __builtin_amdgcn_mfma_f32_16x16x32_bf16(pb, bu, ob, 0, 0, 0);
      }
#pragma unroll
      for (int reg = 0; reg < 4; ++reg) {
        int ra = base + m0 + quad * 4 + reg;
        Obf[(size_t)ra * 1024 + c0 + l16] = f2bf(oa[reg]);
        Obf[(size_t)(ra + 64) * 1024 + c0 + l16] = f2bf(ob[reg]);
      }
    }

    // ---- phase C: Sreg += u^T K over t=128 (wave owns d0w..d0w+127) ----
    {
      short8 uf0 = *reinterpret_cast<const short8*>(&uT[l16][0 * 32 + quad * 8]);
      short8 uf1 = *reinterpret_cast<const short8*>(&uT[l16][1 * 32 + quad * 8]);
      short8 uf2 = *reinterpret_cast<const short8*>(&uT[l16][2 * 32 + quad * 8]);
      short8 uf3 = *reinterpret_cast<const short8*>(&uT[l16][3 * 32 + quad * 8]);
      const u16* ktb = KT + ((size_t)b * 1024 + d0w + l16) * tgs + (size_t)cc * 128 + quad * 8;
#pragma unroll
      for (int nt = 0; nt < 8; ++nt) {
        const u16* kr = ktb + (size_t)(nt * 16) * tgs;
        floatx4 cf = Sreg[nt];
        cf = __builtin_amdgcn_mfma_f32_16x16x32_bf16(uf0, *reinterpret_cast<const short8*>(kr + 0),  cf, 0, 0, 0);
        cf = __builtin_amdgcn_mfma_f32_16x16x32_bf16(uf1, *reinterpret_cast<const short8*>(kr + 32), cf, 0, 0, 0);
        cf = __builtin_amdgcn_mfma_f32_16x16x32_bf16(uf2, *reinterpret_cast<const short8*>(kr + 64), cf, 0, 0, 0);
        cf = __builtin_amdgcn_mfma_f32_16x16x32_bf16(uf3, *reinterpret_cast<const short8*>(kr + 96), cf, 0, 0, 0);
        Sreg[nt] = cf;
        const int dn = d0w + nt * 16;
#pragma unroll
        for (int reg = 0; reg < 4; ++reg)
          Sb[quad * 4 + reg][dn + l16] = f2bf(cf[reg]);
      }
    }
    barrier_lgkm();
  }

  // spill S for next group (small-ws tiers only; full tier has ngrp==1)
  if (g < ngrp - 1) {
#pragma unroll
    for (int nt = 0; nt < 8; ++nt)
#pragma unroll
      for (int reg = 0; reg < 4; ++reg)
        Sglob[((size_t)b * 1024 + c0 + quad * 4 + reg) * 1024 + d0w + nt * 16 + l16] =
            Sreg[nt][reg];
  }
}

// ---------------------------------------------------------------------------
extern "C" void kernel_launch(void* const* d_in, const int* in_sizes, int n_in,
                              void* d_out, int out_size, void* d_ws, size_t ws_size,
                              hipStream_t stream) {
  const float* x  = (const float*)d_in[0];
  const float* Wq = (const float*)d_in[1];
  const float* Wk = (const float*)d_in[2];
  const float* Wv = (const float*)d_in[3];
  const float* Wo = (const float*)d_in[4];
  float* out = (float*)d_out;

  // tier: largest time-group that fits ws
  int lsh = 8;
  {
    const int cand[4] = {11, 10, 9, 8};
    for (int i = 0; i < 4; ++i) {
      size_t tgs = (size_t)1 << cand[i];
      size_t C = (size_t)B_ * tgs * 1024;
      size_t c64 = tgs / 64, c128 = tgs / 128;
      int ng = T_ / (int)tgs;
      size_t need = (size_t)B_ * T_ * 1024 * 2              // Xbf
                  + 4 * ((size_t)1024 * 1024 * 2)           // WT x4
                  + 5 * (C * 2)                             // Qbf,Kbf,Vbf,KT,Obf
                  + 5 * (c64 * B_ * 4096 * 2)               // Pb,Wb,WbT,Mb,Nb
                  + 2 * (c128 * B_ * 16384 * 2)             // W128,P128
                  + (ng > 1 ? (size_t)B_ * 1024 * 1024 * 4 : 0)  // Sglob
                  + 32768;
      if (need <= ws_size) { lsh = cand[i]; break; }
    }
  }
  const int tgs = 1 << lsh;
  const int cpg64 = tgs / 64;
  const int cpg128 = tgs / 128;
  const int ngrp = T_ / tgs;
  const int rows = B_ * tgs;

  char* ws = (char*)d_ws;
  size_t off = 0;
  auto alloc = [&](size_t bytes) -> void* {
    void* p = ws + off;
    off += (bytes + 255) & ~(size_t)255;
    return p;
  };
  u16* Xbf = (u16*)alloc((size_t)B_ * T_ * 1024 * 2);
  u16* WqT = (u16*)alloc((size_t)1024 * 1024 * 2);
  u16* WkT = (u16*)alloc((size_t)1024 * 1024 * 2);
  u16* WvT = (u16*)alloc((size_t)1024 * 1024 * 2);
  u16* WoT = (u16*)alloc((size_t)1024 * 1024 * 2);
  u16* Qbf = (u16*)alloc((size_t)rows * 1024 * 2);
  u16* Kbf = (u16*)alloc((size_t)rows * 1024 * 2);
  u16* Vbf = (u16*)alloc((size_t)rows * 1024 * 2);
  u16* KT  = (u16*)alloc((size_t)rows * 1024 * 2);
  u16* Obf = (u16*)alloc((size_t)rows * 1024 * 2);
  u16* Pb  = (u16*)alloc((size_t)cpg64 * B_ * 4096 * 2);
  u16* Wb  = (u16*)alloc((size_t)cpg64 * B_ * 4096 * 2);
  u16* WbT = (u16*)alloc((size_t)cpg64 * B_ * 4096 * 2);
  u16* Mb  = (u16*)alloc((size_t)cpg64 * B_ * 4096 * 2);
  u16* Nb  = (u16*)alloc((size_t)cpg64 * B_ * 4096 * 2);
  u16* W128 = (u16*)alloc((size_t)cpg128 * B_ * 16384 * 2);
  u16* P128 = (u16*)alloc((size_t)cpg128 * B_ * 16384 * 2);
  float* Sglob = (ngrp > 1) ? (float*)alloc((size_t)B_ * 1024 * 1024 * 4)
                            : (float*)ws;   // unused when ngrp==1

  xconv_kernel<<<B_ * T_, 256, 0, stream>>>(x, Xbf);
  wtrans_kernel<<<dim3(16, 16, 4), 256, 0, stream>>>(Wq, Wk, Wv, Wo, WqT, WkT, WvT, WoT);

  for (int g = 0; g < ngrp; ++g) {
    int tg = g * tgs;
    mgemm_qkv<<<dim3(rows / 128, 8, 3), 256, 0, stream>>>(Xbf, WqT, WkT, WvT,
                                                          Qbf, Kbf, Vbf, tg, lsh);
    knorm_kernel<<<rows, 256, 0, stream>>>(Kbf);
    ktrans_kernel<<<dim3(tgs / 64, 16, B_), 256, 0, stream>>>(Kbf, KT, tgs);
    attn_winv_kernel<<<dim3(cpg64, B_), 256, 0, stream>>>(Qbf, Kbf, Pb, Wb, WbT,
                                                          Mb, Nb, tgs);
    wcomp_kernel<<<dim3(cpg128, B_), 256, 0, stream>>>(Pb, Wb, WbT, Mb, Nb,
                                                       W128, P128);
    chain_kernel<<<256, 512, 0, stream>>>(Qbf, Kbf, KT, Vbf, Obf, W128, P128,
                                          Sglob, lsh, cpg128, g, ngrp);
    mgemm_out<<<dim3(rows / 128, 8), 256, 0, stream>>>(Obf, WoT, out, tg, lsh);
  }
}

// Round 10
// 622.171 us; speedup vs baseline: 1.1284x; 1.1284x over previous
//
#include <hip/hip_runtime.h>

typedef unsigned short u16;
typedef __attribute__((ext_vector_type(8))) short short8;     // 8 bf16 (4 VGPRs)
typedef __attribute__((ext_vector_type(4))) float floatx4;    // 4 fp32 acc

#define B_ 4
#define T_ 2048
#define CH 64

__device__ __forceinline__ u16 f2bf(float f) {
  unsigned int x = __float_as_uint(f);
  return (u16)((x + 0x7FFFu + ((x >> 16) & 1u)) >> 16);
}
__device__ __forceinline__ float bf2f(u16 u) {
  union { unsigned int i; float f; } v; v.i = ((unsigned int)u) << 16; return v.f;
}

// lgkm-only barrier: all cross-wave hazards in chain_kernel are LDS.
__device__ __forceinline__ void barrier_lgkm() {
  asm volatile("s_waitcnt lgkmcnt(0)\n\ts_barrier" ::: "memory");
}

// Opaque asm loads: compiler cannot sink/duplicate/rematerialize these, so
// issue points and the hand-counted vmcnt ledger are exact.
#define GL(dst, addr, IMM) \
  asm volatile("global_load_dwordx4 %0, %1, off offset:" #IMM : "=v"(dst) : "v"(addr))
#define GLU(dst, addr, IMM) \
  asm volatile("global_load_ushort %0, %1, off offset:" #IMM : "=v"(dst) : "v"(addr))
#define GS(addr, val, IMM) \
  asm volatile("global_store_short %0, %1, off offset:" #IMM :: "v"(addr), "v"(val))

#define GLA(slot, base, I0, I1, I2, I3) do { \
  GL(af[slot][0], base, I0); GL(af[slot][1], base, I1); \
  GL(af[slot][2], base, I2); GL(af[slot][3], base, I3); } while (0)

#define GLKT(nt0) do { \
  const u16* kp0_ = ktbn + (size_t)(nt0) * ktstep; \
  GL(ktf[nt0][0], kp0_, 0); GL(ktf[nt0][1], kp0_, 64); \
  const u16* kp1_ = ktbn + (size_t)(nt0 + 1) * ktstep; \
  GL(ktf[nt0 + 1][0], kp1_, 0); GL(ktf[nt0 + 1][1], kp1_, 64); } while (0)

// One phase-A iteration: counted wait, af-only prefetch (depth-2), LDS
// B-frags + 4 MFMAs. sched_barrier(0x387) keeps MFMAs below the wait
// (rule #18: MFMA otherwise hoists past inline-asm waitcnt).
#define A_IT(K, NW, PREFETCH) do { \
  asm volatile("s_waitcnt vmcnt(" #NW ")"); \
  __builtin_amdgcn_sched_barrier(0x387); \
  PREFETCH; \
  short8 b0_ = *reinterpret_cast<const short8*>(&Sb[l16][(K * 4 + 0) * 32 + quad * 8]); \
  short8 b1_ = *reinterpret_cast<const short8*>(&Sb[l16][(K * 4 + 1) * 32 + quad * 8]); \
  short8 b2_ = *reinterpret_cast<const short8*>(&Sb[l16][(K * 4 + 2) * 32 + quad * 8]); \
  short8 b3_ = *reinterpret_cast<const short8*>(&Sb[l16][(K * 4 + 3) * 32 + quad * 8]); \
  ac0 = __builtin_amdgcn_mfma_f32_16x16x32_bf16(af[K][0], b0_, ac0, 0, 0, 0); \
  ac1 = __builtin_amdgcn_mfma_f32_16x16x32_bf16(af[K][1], b1_, ac1, 0, 0, 0); \
  ac2 = __builtin_amdgcn_mfma_f32_16x16x32_bf16(af[K][2], b2_, ac2, 0, 0, 0); \
  ac3 = __builtin_amdgcn_mfma_f32_16x16x32_bf16(af[K][3], b3_, ac3, 0, 0, 0); \
} while (0)

// ---------------------------------------------------------------------------
// x fp32 -> bf16 (full tensor). grid (B_*T_), 256 thr x 4 elems.
// ---------------------------------------------------------------------------
__global__ __launch_bounds__(256) void xconv_kernel(const float* __restrict__ x,
                                                    u16* __restrict__ Xbf) {
  size_t idx = ((size_t)blockIdx.x * 256 + threadIdx.x) * 4;
  float4 v = *reinterpret_cast<const float4*>(&x[idx]);
  ushort4 o;
  o.x = f2bf(v.x); o.y = f2bf(v.y); o.z = f2bf(v.z); o.w = f2bf(v.w);
  *reinterpret_cast<ushort4*>(&Xbf[idx]) = o;
}

// ---------------------------------------------------------------------------
// Weight transpose+convert: T[n][k] = bf16(W[k][n]). grid (16,16,4).
// ---------------------------------------------------------------------------
__global__ __launch_bounds__(256) void wtrans_kernel(
    const float* __restrict__ W0, const float* __restrict__ W1,
    const float* __restrict__ W2, const float* __restrict__ W3,
    u16* __restrict__ T0, u16* __restrict__ T1,
    u16* __restrict__ T2, u16* __restrict__ T3)
{
  const int z = blockIdx.z;
  const float* W = (z == 0) ? W0 : (z == 1) ? W1 : (z == 2) ? W2 : W3;
  u16* T = (z == 0) ? T0 : (z == 1) ? T1 : (z == 2) ? T2 : T3;
  const int k0 = blockIdx.x * 64, n0 = blockIdx.y * 64;
  const int tid = threadIdx.x;
  __shared__ float Tile[64][65];
#pragma unroll
  for (int i = 0; i < 4; ++i) {
    int lin = tid + i * 256;
    int r = lin >> 4, c4 = (lin & 15) * 4;
    *reinterpret_cast<float4*>(&Tile[r][c4]) =
        *reinterpret_cast<const float4*>(&W[(size_t)(k0 + r) * 1024 + n0 + c4]);
  }
  __syncthreads();
#pragma unroll
  for (int i = 0; i < 4; ++i) {
    int lin = tid + i * 256;
    int r = lin >> 4, c4 = (lin & 15) * 4;   // r: n-within, c4: k-within
    ushort4 o;
    o.x = f2bf(Tile[c4 + 0][r]); o.y = f2bf(Tile[c4 + 1][r]);
    o.z = f2bf(Tile[c4 + 2][r]); o.w = f2bf(Tile[c4 + 3][r]);
    *reinterpret_cast<ushort4*>(&T[(size_t)(n0 + r) * 1024 + k0 + c4]) = o;
  }
}

// ---------------------------------------------------------------------------
// MFMA GEMM for QKV. 128x128 tile, 4 waves (2x2), 4x4 of 16x16x32, BK=32.
// grid (rows/128, 8, 3).
// ---------------------------------------------------------------------------
__global__ __launch_bounds__(256) void mgemm_qkv(
    const u16* __restrict__ Xbf,
    const u16* __restrict__ WqT, const u16* __restrict__ WkT, const u16* __restrict__ WvT,
    u16* __restrict__ Qbf, u16* __restrict__ Kbf, u16* __restrict__ Vbf,
    int tg, int lsh)
{
  const int z = blockIdx.z;
  const u16* BT = (z == 0) ? WqT : ((z == 1) ? WkT : WvT);
  u16* O = (z == 0) ? Qbf : ((z == 1) ? Kbf : Vbf);
  const float scale = (z == 0) ? 0.03125f : 1.0f;
  const int r0 = blockIdx.x * 128, c0 = blockIdx.y * 128;
  const int tid = threadIdx.x;
  const int lane = tid & 63, wave = tid >> 6;
  const int quad = lane >> 4, l16 = lane & 15;
  const int wr = (wave >> 1) * 64, wc = (wave & 1) * 64;

  __shared__ u16 As[128][40];
  __shared__ u16 Bs[128][40];

  const int ar = tid >> 1, ac = (tid & 1) * 16;
  const int lr = r0 + ar;
  const int agrow = ((lr >> lsh) << 11) + tg + (lr & ((1 << lsh) - 1));
  const u16* aptr = &Xbf[(size_t)agrow * 1024 + ac];
  const u16* bptr = &BT[(size_t)(c0 + ar) * 1024 + ac];

  floatx4 acc[4][4] = {};
  for (int k0 = 0; k0 < 1024; k0 += 32) {
    float4 av0 = *reinterpret_cast<const float4*>(aptr + k0);
    float4 av1 = *reinterpret_cast<const float4*>(aptr + k0 + 8);
    float4 bv0 = *reinterpret_cast<const float4*>(bptr + k0);
    float4 bv1 = *reinterpret_cast<const float4*>(bptr + k0 + 8);
    __syncthreads();
    *reinterpret_cast<float4*>(&As[ar][ac]) = av0;
    *reinterpret_cast<float4*>(&As[ar][ac + 8]) = av1;
    *reinterpret_cast<float4*>(&Bs[ar][ac]) = bv0;
    *reinterpret_cast<float4*>(&Bs[ar][ac + 8]) = bv1;
    __syncthreads();
    short8 afr[4], bfr[4];
#pragma unroll
    for (int i = 0; i < 4; ++i) {
      afr[i] = *reinterpret_cast<const short8*>(&As[wr + i * 16 + l16][quad * 8]);
      bfr[i] = *reinterpret_cast<const short8*>(&Bs[wc + i * 16 + l16][quad * 8]);
    }
#pragma unroll
    for (int mi = 0; mi < 4; ++mi)
#pragma unroll
      for (int ni = 0; ni < 4; ++ni)
        acc[mi][ni] = __builtin_amdgcn_mfma_f32_16x16x32_bf16(afr[mi], bfr[ni], acc[mi][ni], 0, 0, 0);
  }
#pragma unroll
  for (int mi = 0; mi < 4; ++mi)
#pragma unroll
    for (int reg = 0; reg < 4; ++reg) {
      int row = r0 + wr + mi * 16 + quad * 4 + reg;
#pragma unroll
      for (int ni = 0; ni < 4; ++ni) {
        int col = c0 + wc + ni * 16 + l16;
        O[(size_t)row * 1024 + col] = f2bf(acc[mi][ni][reg] * scale);
      }
    }
}

// ---------------------------------------------------------------------------
// MFMA GEMM out-proj: fp32 out. grid (rows/128, 8)
// ---------------------------------------------------------------------------
__global__ __launch_bounds__(256) void mgemm_out(
    const u16* __restrict__ Obf, const u16* __restrict__ WoT,
    float* __restrict__ out, int tg, int lsh)
{
  const int r0 = blockIdx.x * 128, c0 = blockIdx.y * 128;
  const int tid = threadIdx.x;
  const int lane = tid & 63, wave = tid >> 6;
  const int quad = lane >> 4, l16 = lane & 15;
  const int wr = (wave >> 1) * 64, wc = (wave & 1) * 64;

  __shared__ u16 As[128][40];
  __shared__ u16 Bs[128][40];

  const int ar = tid >> 1, ac = (tid & 1) * 16;
  const u16* aptr = &Obf[(size_t)(r0 + ar) * 1024 + ac];
  const u16* bptr = &WoT[(size_t)(c0 + ar) * 1024 + ac];

  floatx4 acc[4][4] = {};
  for (int k0 = 0; k0 < 1024; k0 += 32) {
    float4 av0 = *reinterpret_cast<const float4*>(aptr + k0);
    float4 av1 = *reinterpret_cast<const float4*>(aptr + k0 + 8);
    float4 bv0 = *reinterpret_cast<const float4*>(bptr + k0);
    float4 bv1 = *reinterpret_cast<const float4*>(bptr + k0 + 8);
    __syncthreads();
    *reinterpret_cast<float4*>(&As[ar][ac]) = av0;
    *reinterpret_cast<float4*>(&As[ar][ac + 8]) = av1;
    *reinterpret_cast<float4*>(&Bs[ar][ac]) = bv0;
    *reinterpret_cast<float4*>(&Bs[ar][ac + 8]) = bv1;
    __syncthreads();
    short8 afr[4], bfr[4];
#pragma unroll
    for (int i = 0; i < 4; ++i) {
      afr[i] = *reinterpret_cast<const short8*>(&As[wr + i * 16 + l16][quad * 8]);
      bfr[i] = *reinterpret_cast<const short8*>(&Bs[wc + i * 16 + l16][quad * 8]);
    }
#pragma unroll
    for (int mi = 0; mi < 4; ++mi)
#pragma unroll
      for (int ni = 0; ni < 4; ++ni)
        acc[mi][ni] = __builtin_amdgcn_mfma_f32_16x16x32_bf16(afr[mi], bfr[ni], acc[mi][ni], 0, 0, 0);
  }
#pragma unroll
  for (int mi = 0; mi < 4; ++mi)
#pragma unroll
    for (int reg = 0; reg < 4; ++reg) {
      int lr = r0 + wr + mi * 16 + quad * 4 + reg;
      int grow = ((lr >> lsh) << 11) + tg + (lr & ((1 << lsh) - 1));
#pragma unroll
      for (int ni = 0; ni < 4; ++ni) {
        int col = c0 + wc + ni * 16 + l16;
        out[(size_t)grow * 1024 + col] = acc[mi][ni][reg];
      }
    }
}

// ---------------------------------------------------------------------------
// Row-normalize Kbf in place (bf16, fp32 math). grid (rows).
// ---------------------------------------------------------------------------
__global__ __launch_bounds__(256) void knorm_kernel(u16* __restrict__ Kbf) {
  const int row = blockIdx.x;
  const int tid = threadIdx.x;
  ushort4 v4 = *reinterpret_cast<const ushort4*>(&Kbf[(size_t)row * 1024 + tid * 4]);
  float a = bf2f(v4.x), b = bf2f(v4.y), c = bf2f(v4.z), d = bf2f(v4.w);
  float ss = a * a + b * b + c * c + d * d;
#pragma unroll
  for (int off = 32; off > 0; off >>= 1) ss += __shfl_down(ss, off);
  __shared__ float wsum[4];
  if ((tid & 63) == 0) wsum[tid >> 6] = ss;
  __syncthreads();
  float tot = wsum[0] + wsum[1] + wsum[2] + wsum[3];
  float inv = 1.0f / fmaxf(sqrtf(tot), 1e-12f);
  ushort4 o;
  o.x = f2bf(a * inv); o.y = f2bf(b * inv); o.z = f2bf(c * inv); o.w = f2bf(d * inv);
  *reinterpret_cast<ushort4*>(&Kbf[(size_t)row * 1024 + tid * 4]) = o;
}

// ---------------------------------------------------------------------------
// Transpose Kbf -> KT[b][d][t_local] (bf16). grid (tgs/64, 16, B_), 256 thr.
// ---------------------------------------------------------------------------
__global__ __launch_bounds__(256) void ktrans_kernel(const u16* __restrict__ Kbf,
                                                     u16* __restrict__ KT,
                                                     int tgs) {
  const int t0 = blockIdx.x * 64;
  const int d0 = blockIdx.y * 64;
  const int b = blockIdx.z;
  const int tid = threadIdx.x;
  __shared__ u16 Tile[64][68];
#pragma unroll
  for (int i = 0; i < 4; ++i) {
    int lin = tid + i * 256;
    int r = lin >> 4, c4 = (lin & 15) * 4;
    *reinterpret_cast<ushort4*>(&Tile[r][c4]) =
        *reinterpret_cast<const ushort4*>(&Kbf[(size_t)(b * tgs + t0 + r) * 1024 + d0 + c4]);
  }
  __syncthreads();
#pragma unroll
  for (int i = 0; i < 4; ++i) {
    int lin = tid + i * 256;
    int r = lin >> 4, c4 = (lin & 15) * 4;
    ushort4 o;
    o.x = Tile[c4 + 0][r]; o.y = Tile[c4 + 1][r];
    o.z = Tile[c4 + 2][r]; o.w = Tile[c4 + 3][r];
    *reinterpret_cast<ushort4*>(&KT[((size_t)b * 1024 + d0 + r) * tgs + t0 + c4]) = o;
  }
}

// ---------------------------------------------------------------------------
// Per (chunk, batch): MFMA QK^T/KK^T -> P and A -> W=(I+A)^{-1} -> bf16.
// grid (cpg, B_), 256 threads.
// ---------------------------------------------------------------------------
__global__ __launch_bounds__(256) void attn_winv_kernel(
    const u16* __restrict__ Qbf, const u16* __restrict__ Kbf,
    u16* __restrict__ Pb, u16* __restrict__ Wb, int tgs)
{
  const int cc = blockIdx.x;
  const int b = blockIdx.y;
  const int base = b * tgs + cc * CH;
  const int tid = threadIdx.x;
  const int lane = tid & 63;
  const int wave = tid >> 6;
  const int quad = lane >> 4, l16 = lane & 15;
  const int m0 = wave * 16;

  __shared__ float Asm[64][64];
  __shared__ float Wsm[64][65];

  floatx4 accA[4] = {};
  floatx4 accP[4] = {};
  const u16* arowK = &Kbf[(size_t)(base + m0 + l16) * 1024];
  const u16* arowQ = &Qbf[(size_t)(base + m0 + l16) * 1024];
#pragma unroll 4
  for (int kk = 0; kk < 32; ++kk) {
    short8 aK = *reinterpret_cast<const short8*>(&arowK[kk * 32 + quad * 8]);
    short8 aQ = *reinterpret_cast<const short8*>(&arowQ[kk * 32 + quad * 8]);
#pragma unroll
    for (int nt = 0; nt < 4; ++nt) {
      short8 bK = *reinterpret_cast<const short8*>(
          &Kbf[(size_t)(base + nt * 16 + l16) * 1024 + kk * 32 + quad * 8]);
      accA[nt] = __builtin_amdgcn_mfma_f32_16x16x32_bf16(aK, bK, accA[nt], 0, 0, 0);
      accP[nt] = __builtin_amdgcn_mfma_f32_16x16x32_bf16(aQ, bK, accP[nt], 0, 0, 0);
    }
  }
  const size_t pw0 = ((size_t)(cc * B_ + b) * CH) * 64;
#pragma unroll
  for (int nt = 0; nt < 4; ++nt) {
#pragma unroll
    for (int reg = 0; reg < 4; ++reg) {
      int t = m0 + quad * 4 + reg;
      int i = nt * 16 + l16;
      Asm[t][i] = (i < t) ? accA[nt][reg] : 0.0f;
      Pb[pw0 + (size_t)t * 64 + i] = f2bf((i <= t) ? accP[nt][reg] : 0.0f);
    }
  }
  __syncthreads();

  if (tid < 64) {
    const int j = tid;
    for (int t = 0; t < 64; ++t) {
      float s = (t == j) ? 1.0f : 0.0f;
      for (int i = 0; i < t; ++i) s -= Asm[t][i] * Wsm[i][j];
      Wsm[t][j] = s;
    }
    for (int t = 0; t < 64; ++t)
      Wb[pw0 + (size_t)t * 64 + j] = f2bf(Wsm[t][j]);
  }
}

// ---------------------------------------------------------------------------
// Persistent-state MFMA chain, v7: TA-issue spreading on the v3 base.
// DIAGNOSIS (v1-v6): per-CU per-chunk ~880KB of VMEM at 64B/cy TA/L1 pipe
// = 5.7us/chunk hard floor; measured 12us -> ~2.2x overlap inefficiency:
// v3 crowded ALL ~54 loads/wave into phase A's window, leaving TA idle
// through rhs/u/o/C (~4-6k cy/chunk). v7 spreads issue: A_ITs issue ONLY
// the af depth-2 pipeline; next chunk's ktf issue right after phase C
// (its consumer), wpf/vv issue after o (their consumers). No gate-wait
// before rhs (vv/wpf/ktf all retired by A_IT2's wait(4)).
// Ledger (both roles; Q-stores at o only strengthen later waits):
//   entry outstanding 30 = [af0,af1,ktf16,wpf2,vv4];
//   A_IT waits: 26,26,4,4,4,4,4,4; o reads wpf BEFORE wpf' issue.
// ---------------------------------------------------------------------------
__global__ __launch_bounds__(512, 2) void chain_kernel(
    const u16* __restrict__ Qbf, const u16* __restrict__ Kbf,
    const u16* __restrict__ KT, const u16* __restrict__ Vbf,
    u16* __restrict__ Obf, const u16* __restrict__ Wb, const u16* __restrict__ Pb,
    float* __restrict__ Sglob, int lsh, int cpg, int g, int ngrp)
{
  const int wg = blockIdx.x;
  // XCD pair {2b, 2b+1} hosts exactly batch b's 64 slices (bijective).
  const int t8 = wg & 7;
  const int b = t8 >> 1;
  const int sl = ((wg >> 3) << 1) | (t8 & 1);
  const int c0 = sl * 16;
  const int tgs = 1 << lsh;
  const int tid = threadIdx.x;
  const int lane = tid & 63;
  const int wave = tid >> 6;
  const int quad = lane >> 4, l16 = lane & 15;
  const int d0w = wave * 128;
  const bool isK = (wave < 4);
  const int m0 = (isK ? wave : (wave - 4)) * 16;
  const size_t ktstep = (size_t)16 * tgs;

  __shared__ u16 Sb[16][1048];   // bf16 shadow (524 words/row = 12 mod 32)
  __shared__ u16 rhsT[16][88];   // (V - KS)^T bf16
  __shared__ u16 uT[16][88];     // u^T bf16

  // fp32 master S: Sreg[nt][reg] <-> S[c=quad*4+reg][d=d0w+nt*16+l16]
  floatx4 Sreg[8];
  if (g == 0) {
#pragma unroll
    for (int nt = 0; nt < 8; ++nt) Sreg[nt] = (floatx4){0.f, 0.f, 0.f, 0.f};
    for (int idx = tid; idx < 16 * 256; idx += 512) {
      int r = idx >> 8, d4 = (idx & 255) * 4;
      ushort4 z4 = {0, 0, 0, 0};
      *reinterpret_cast<ushort4*>(&Sb[r][d4]) = z4;
    }
  } else {
#pragma unroll
    for (int nt = 0; nt < 8; ++nt)
#pragma unroll
      for (int reg = 0; reg < 4; ++reg)
        Sreg[nt][reg] = Sglob[((size_t)b * 1024 + c0 + quad * 4 + reg) * 1024 +
                              d0w + nt * 16 + l16];
    for (int idx = tid; idx < 16 * 1024; idx += 512) {
      int r = idx >> 10, d = idx & 1023;
      Sb[r][d] = f2bf(Sglob[((size_t)b * 1024 + c0 + r) * 1024 + d]);
    }
  }
  __syncthreads();   // drains vmcnt: ledger starts at 0

  const u16* const Abase = isK ? Kbf : Qbf;
  const u16* const WPbase = isK ? Wb : Pb;

  short8 af[8][4];    // A-frag ring; slot k holds iter-k frags
  short8 ktf[8][2];
  short8 wpf0, wpf1;
  unsigned int vv0, vv1, vv2, vv3;

  const u16* arow = Abase + (size_t)(b * tgs + m0 + l16) * 1024;  // chunk 0

  // Prologue (chunk 0), issue order MUST match steady entry:
  // af0, af1, ktf16, wpf2, vv4  -> 30 outstanding.
  {
    const u16* aq0 = arow + quad * 8;
    GLA(0, aq0, 0, 64, 128, 192);
    GLA(1, aq0, 256, 320, 384, 448);
    const u16* ktbn = KT + ((size_t)b * 1024 + d0w + l16) * tgs + quad * 8;
    GLKT(0); GLKT(2); GLKT(4); GLKT(6);
    const u16* wrow0 = WPbase + (size_t)(b * CH * 0 + 0) + ((size_t)(0 * B_ + b) * CH) * 64 +
                       (size_t)(m0 + l16) * 64 + quad * 8;
    GL(wpf0, wrow0, 0); GL(wpf1, wrow0, 64);
    const u16* vvb0  = Vbf + (size_t)(b * tgs + m0 + quad * 4) * 1024 + c0 + l16;
    const u16* vvb02 = vvb0 + 2048;
    GLU(vv0, vvb0, 0); GLU(vv1, vvb0, 2048);
    GLU(vv2, vvb02, 0); GLU(vv3, vvb02, 2048);
  }

  for (int cc = 0; cc < cpg; ++cc) {
    const int base = b * tgs + cc * CH;
    const int nx = (cc + 1 < cpg) ? (cc + 1) : (cpg - 1);

    const u16* aq  = arow + quad * 8;
    const u16* aqn = arow + (size_t)(cc + 1 < cpg ? CH * 1024 : 0) + quad * 8;

    floatx4 ac0 = {}, ac1 = {}, ac2 = {}, ac3 = {};

    // ---- phase A: af-only issue (depth-2 ring); waits retire the older
    //      ktf/wpf/vv(cc) groups implicitly (issued last chunk, done). ----
    A_IT(0, 26, GLA(2, aq, 512, 576, 640, 704));
    A_IT(1, 26, GLA(3, aq, 768, 832, 896, 960));
    A_IT(2, 4,  GLA(4, aq, 1024, 1088, 1152, 1216));
    A_IT(3, 4,  GLA(5, aq, 1280, 1344, 1408, 1472));
    A_IT(4, 4,  GLA(6, aq, 1536, 1600, 1664, 1728));
    A_IT(5, 4,  GLA(7, aq, 1792, 1856, 1920, 1984));
    A_IT(6, 4,  GLA(0, aqn, 0, 64, 128, 192));
    A_IT(7, 4,  GLA(1, aqn, 256, 320, 384, 448));

    floatx4 accS = (ac0 + ac1) + (ac2 + ac3);

    // ---- rhs = V - KS (K-waves); vv retired at A_IT2's wait(4) ----
    if (isK) {
      rhsT[l16][m0 + quad * 4 + 0] = f2bf(bf2f((u16)vv0) - accS[0]);
      rhsT[l16][m0 + quad * 4 + 1] = f2bf(bf2f((u16)vv1) - accS[1]);
      rhsT[l16][m0 + quad * 4 + 2] = f2bf(bf2f((u16)vv2) - accS[2]);
      rhsT[l16][m0 + quad * 4 + 3] = f2bf(bf2f((u16)vv3) - accS[3]);
    }
    barrier_lgkm();

    // ---- u = W * rhs (K-waves) ----
    if (isK) {
      floatx4 uacc = {};
      short8 br0 = *reinterpret_cast<const short8*>(&rhsT[l16][quad * 8]);
      short8 br1 = *reinterpret_cast<const short8*>(&rhsT[l16][32 + quad * 8]);
      uacc = __builtin_amdgcn_mfma_f32_16x16x32_bf16(wpf0, br0, uacc, 0, 0, 0);
      uacc = __builtin_amdgcn_mfma_f32_16x16x32_bf16(wpf1, br1, uacc, 0, 0, 0);
#pragma unroll
      for (int reg = 0; reg < 4; ++reg)
        uT[l16][m0 + quad * 4 + reg] = f2bf(uacc[reg]);
    }
    barrier_lgkm();

    short8 ua0 = *reinterpret_cast<const short8*>(&uT[l16][quad * 8]);
    short8 ua1 = *reinterpret_cast<const short8*>(&uT[l16][32 + quad * 8]);

    // ---- phase C: Sreg += u^T K (consumes ktf(cc)) ----
    {
#pragma unroll
      for (int nt = 0; nt < 8; ++nt) {
        floatx4 cf = Sreg[nt];
        cf = __builtin_amdgcn_mfma_f32_16x16x32_bf16(ua0, ktf[nt][0], cf, 0, 0, 0);
        cf = __builtin_amdgcn_mfma_f32_16x16x32_bf16(ua1, ktf[nt][1], cf, 0, 0, 0);
        Sreg[nt] = cf;
        const int dn = d0w + nt * 16;
#pragma unroll
        for (int reg = 0; reg < 4; ++reg)
          Sb[quad * 4 + reg][dn + l16] = f2bf(cf[reg]);
      }
    }

    // ---- issue ktf(cc+1): fills the TA pipe during the C/o window ----
    {
      const u16* ktbn = KT + ((size_t)b * 1024 + d0w + l16) * tgs +
                        (size_t)nx * CH + quad * 8;
      GLKT(0); GLKT(2); GLKT(4); GLKT(6);
    }

    // ---- o = QS + P*u (Q-waves, reads wpf(cc) BEFORE wpf' issue) ----
    if (!isK) {
      floatx4 oacc = accS;
      oacc = __builtin_amdgcn_mfma_f32_16x16x32_bf16(wpf0, ua0, oacc, 0, 0, 0);
      oacc = __builtin_amdgcn_mfma_f32_16x16x32_bf16(wpf1, ua1, oacc, 0, 0, 0);
      u16* ob  = Obf + (size_t)(base + m0 + quad * 4) * 1024 + c0 + l16;
      u16* ob2 = ob + 2048;
      unsigned int s0 = f2bf(oacc[0]), s1 = f2bf(oacc[1]);
      unsigned int s2 = f2bf(oacc[2]), s3 = f2bf(oacc[3]);
      GS(ob, s0, 0);  GS(ob, s1, 2048);
      GS(ob2, s2, 0); GS(ob2, s3, 2048);
    }

    // ---- issue wpf(cc+1), vv(cc+1) ----
    {
      const size_t pwN = ((size_t)(nx * B_ + b) * CH) * 64;
      const u16* wrow = WPbase + pwN + (size_t)(m0 + l16) * 64 + quad * 8;
      GL(wpf0, wrow, 0); GL(wpf1, wrow, 64);
      const u16* vvb  = Vbf + (size_t)(b * tgs + nx * CH + m0 + quad * 4) * 1024 + c0 + l16;
      const u16* vvb2 = vvb + 2048;
      GLU(vv0, vvb, 0); GLU(vv1, vvb, 2048);
      GLU(vv2, vvb2, 0); GLU(vv3, vvb2, 2048);
    }

    barrier_lgkm();
    arow += CH * 1024;
  }

  asm volatile("s_waitcnt vmcnt(0)");   // retire in-flight asm loads/stores

  // spill S for next group (small-ws tiers only; full tier has ngrp==1)
  if (g < ngrp - 1) {
#pragma unroll
    for (int nt = 0; nt < 8; ++nt)
#pragma unroll
      for (int reg = 0; reg < 4; ++reg)
        Sglob[((size_t)b * 1024 + c0 + quad * 4 + reg) * 1024 + d0w + nt * 16 + l16] =
            Sreg[nt][reg];
  }
}

// ---------------------------------------------------------------------------
extern "C" void kernel_launch(void* const* d_in, const int* in_sizes, int n_in,
                              void* d_out, int out_size, void* d_ws, size_t ws_size,
                              hipStream_t stream) {
  const float* x  = (const float*)d_in[0];
  const float* Wq = (const float*)d_in[1];
  const float* Wk = (const float*)d_in[2];
  const float* Wv = (const float*)d_in[3];
  const float* Wo = (const float*)d_in[4];
  float* out = (float*)d_out;

  // tier: largest time-group that fits ws
  int lsh = 8;
  {
    const int cand[4] = {11, 10, 9, 8};
    for (int i = 0; i < 4; ++i) {
      size_t tgs = (size_t)1 << cand[i];
      size_t C = (size_t)B_ * tgs * 1024;
      size_t cpg = tgs / CH;
      size_t need = (size_t)B_ * T_ * 1024 * 2              // Xbf
                  + 4 * ((size_t)1024 * 1024 * 2)           // WT x4
                  + 5 * (C * 2)                             // Qbf,Kbf,Vbf,KT,Obf
                  + 2 * (cpg * B_ * CH * 64 * 2)            // Pb,Wb
                  + (size_t)B_ * 1024 * 1024 * 4            // Sglob
                  + 32768;
      if (need <= ws_size) { lsh = cand[i]; break; }
    }
  }
  const int tgs = 1 << lsh;
  const int cpg = tgs / CH;
  const int ngrp = T_ / tgs;
  const int rows = B_ * tgs;

  char* ws = (char*)d_ws;
  size_t off = 0;
  auto alloc = [&](size_t bytes) -> void* {
    void* p = ws + off;
    off += (bytes + 255) & ~(size_t)255;
    return p;
  };
  u16* Xbf = (u16*)alloc((size_t)B_ * T_ * 1024 * 2);
  u16* WqT = (u16*)alloc((size_t)1024 * 1024 * 2);
  u16* WkT = (u16*)alloc((size_t)1024 * 1024 * 2);
  u16* WvT = (u16*)alloc((size_t)1024 * 1024 * 2);
  u16* WoT = (u16*)alloc((size_t)1024 * 1024 * 2);
  u16* Qbf = (u16*)alloc((size_t)rows * 1024 * 2);
  u16* Kbf = (u16*)alloc((size_t)rows * 1024 * 2);
  u16* Vbf = (u16*)alloc((size_t)rows * 1024 * 2);
  u16* KT  = (u16*)alloc((size_t)rows * 1024 * 2);
  u16* Obf = (u16*)alloc((size_t)rows * 1024 * 2);
  u16* Pb  = (u16*)alloc((size_t)cpg * B_ * CH * 64 * 2);
  u16* Wb  = (u16*)alloc((size_t)cpg * B_ * CH * 64 * 2);
  float* Sglob = (float*)alloc((size_t)B_ * 1024 * 1024 * 4);

  xconv_kernel<<<B_ * T_, 256, 0, stream>>>(x, Xbf);
  wtrans_kernel<<<dim3(16, 16, 4), 256, 0, stream>>>(Wq, Wk, Wv, Wo, WqT, WkT, WvT, WoT);

  for (int g = 0; g < ngrp; ++g) {
    int tg = g * tgs;
    mgemm_qkv<<<dim3(rows / 128, 8, 3), 256, 0, stream>>>(Xbf, WqT, WkT, WvT,
                                                          Qbf, Kbf, Vbf, tg, lsh);
    knorm_kernel<<<rows, 256, 0, stream>>>(Kbf);
    ktrans_kernel<<<dim3(tgs / 64, 16, B_), 256, 0, stream>>>(Kbf, KT, tgs);
    attn_winv_kernel<<<dim3(cpg, B_), 256, 0, stream>>>(Qbf, Kbf, Pb, Wb, tgs);
    chain_kernel<<<256, 512, 0, stream>>>(Qbf, Kbf, KT, Vbf, Obf, Wb, Pb, Sglob,
                                          lsh, cpg, g, ngrp);
    mgemm_out<<<dim3(rows / 128, 8), 256, 0, stream>>>(Obf, WoT, out, tg, lsh);
  }
}

// Round 12
// 613.254 us; speedup vs baseline: 1.1448x; 1.0145x over previous
//
#include <hip/hip_runtime.h>

typedef unsigned short u16;
typedef __attribute__((ext_vector_type(8))) short short8;     // 8 bf16 (4 VGPRs)
typedef __attribute__((ext_vector_type(4))) float floatx4;    // 4 fp32 acc

#define B_ 4
#define T_ 2048
#define CH 64

__device__ __forceinline__ u16 f2bf(float f) {
  unsigned int x = __float_as_uint(f);
  return (u16)((x + 0x7FFFu + ((x >> 16) & 1u)) >> 16);
}
__device__ __forceinline__ float bf2f(u16 u) {
  union { unsigned int i; float f; } v; v.i = ((unsigned int)u) << 16; return v.f;
}

// lgkm-only barrier: all cross-wave hazards in chain_kernel are LDS.
__device__ __forceinline__ void barrier_lgkm() {
  asm volatile("s_waitcnt lgkmcnt(0)\n\ts_barrier" ::: "memory");
}

// Async global->LDS, 16B per lane: LDS dest is WAVE-UNIFORM base + lane*16
// (guide Common-mistake #1 / m97 step-3: compiler never auto-emits this).
__device__ __forceinline__ void gll16(const u16* g, u16* l) {
  __builtin_amdgcn_global_load_lds(
      (const __attribute__((address_space(1))) void*)g,
      (__attribute__((address_space(3))) void*)l, 16, 0, 0);
}

// Opaque asm loads for chain_kernel's hand-counted vmcnt ledger.
#define GL(dst, addr, IMM) \
  asm volatile("global_load_dwordx4 %0, %1, off offset:" #IMM : "=v"(dst) : "v"(addr))
#define GLU(dst, addr, IMM) \
  asm volatile("global_load_ushort %0, %1, off offset:" #IMM : "=v"(dst) : "v"(addr))
#define GS(addr, val, IMM) \
  asm volatile("global_store_short %0, %1, off offset:" #IMM :: "v"(addr), "v"(val))

#define GLA(slot, base, I0, I1, I2, I3) do { \
  GL(af[slot][0], base, I0); GL(af[slot][1], base, I1); \
  GL(af[slot][2], base, I2); GL(af[slot][3], base, I3); } while (0)

#define GLKT(nt0) do { \
  const u16* kp0_ = ktbn + (size_t)(nt0) * ktstep; \
  GL(ktf[nt0][0], kp0_, 0); GL(ktf[nt0][1], kp0_, 64); \
  const u16* kp1_ = ktbn + (size_t)(nt0 + 1) * ktstep; \
  GL(ktf[nt0 + 1][0], kp1_, 0); GL(ktf[nt0 + 1][1], kp1_, 64); } while (0)

#define A_IT(K, NW, PREFETCH) do { \
  asm volatile("s_waitcnt vmcnt(" #NW ")"); \
  __builtin_amdgcn_sched_barrier(0x387); \
  PREFETCH; \
  short8 b0_ = *reinterpret_cast<const short8*>(&Sb[l16][(K * 4 + 0) * 32 + quad * 8]); \
  short8 b1_ = *reinterpret_cast<const short8*>(&Sb[l16][(K * 4 + 1) * 32 + quad * 8]); \
  short8 b2_ = *reinterpret_cast<const short8*>(&Sb[l16][(K * 4 + 2) * 32 + quad * 8]); \
  short8 b3_ = *reinterpret_cast<const short8*>(&Sb[l16][(K * 4 + 3) * 32 + quad * 8]); \
  ac0 = __builtin_amdgcn_mfma_f32_16x16x32_bf16(af[K][0], b0_, ac0, 0, 0, 0); \
  ac1 = __builtin_amdgcn_mfma_f32_16x16x32_bf16(af[K][1], b1_, ac1, 0, 0, 0); \
  ac2 = __builtin_amdgcn_mfma_f32_16x16x32_bf16(af[K][2], b2_, ac2, 0, 0, 0); \
  ac3 = __builtin_amdgcn_mfma_f32_16x16x32_bf16(af[K][3], b3_, ac3, 0, 0, 0); \
} while (0)

// ---------------------------------------------------------------------------
// x fp32 -> bf16 (full tensor). grid (B_*T_), 256 thr x 4 elems.
// ---------------------------------------------------------------------------
__global__ __launch_bounds__(256) void xconv_kernel(const float* __restrict__ x,
                                                    u16* __restrict__ Xbf) {
  size_t idx = ((size_t)blockIdx.x * 256 + threadIdx.x) * 4;
  float4 v = *reinterpret_cast<const float4*>(&x[idx]);
  ushort4 o;
  o.x = f2bf(v.x); o.y = f2bf(v.y); o.z = f2bf(v.z); o.w = f2bf(v.w);
  *reinterpret_cast<ushort4*>(&Xbf[idx]) = o;
}

// ---------------------------------------------------------------------------
// Weight transpose+convert: T[n][k] = bf16(W[k][n]). grid (16,16,4).
// ---------------------------------------------------------------------------
__global__ __launch_bounds__(256) void wtrans_kernel(
    const float* __restrict__ W0, const float* __restrict__ W1,
    const float* __restrict__ W2, const float* __restrict__ W3,
    u16* __restrict__ T0, u16* __restrict__ T1,
    u16* __restrict__ T2, u16* __restrict__ T3)
{
  const int z = blockIdx.z;
  const float* W = (z == 0) ? W0 : (z == 1) ? W1 : (z == 2) ? W2 : W3;
  u16* T = (z == 0) ? T0 : (z == 1) ? T1 : (z == 2) ? T2 : T3;
  const int k0 = blockIdx.x * 64, n0 = blockIdx.y * 64;
  const int tid = threadIdx.x;
  __shared__ float Tile[64][65];
#pragma unroll
  for (int i = 0; i < 4; ++i) {
    int lin = tid + i * 256;
    int r = lin >> 4, c4 = (lin & 15) * 4;
    *reinterpret_cast<float4*>(&Tile[r][c4]) =
        *reinterpret_cast<const float4*>(&W[(size_t)(k0 + r) * 1024 + n0 + c4]);
  }
  __syncthreads();
#pragma unroll
  for (int i = 0; i < 4; ++i) {
    int lin = tid + i * 256;
    int r = lin >> 4, c4 = (lin & 15) * 4;   // r: n-within, c4: k-within
    ushort4 o;
    o.x = f2bf(Tile[c4 + 0][r]); o.y = f2bf(Tile[c4 + 1][r]);
    o.z = f2bf(Tile[c4 + 2][r]); o.w = f2bf(Tile[c4 + 3][r]);
    *reinterpret_cast<ushort4*>(&T[(size_t)(n0 + r) * 1024 + k0 + c4]) = o;
  }
}

// ---------------------------------------------------------------------------
// MFMA GEMM for QKV, m97-style: 128x128 tile, BK=32, global_load_lds w16
// staging into LINEAR As/Bs [128][32] (no pad -- gll writes base+lane*16).
// grid (rows/128, 8, 3). Guide ladder: this structure measures ~874 TF vs
// ~334 TF for the plain-load + padded-LDS variant it replaces.
// ---------------------------------------------------------------------------
__global__ __launch_bounds__(256) void mgemm_qkv(
    const u16* __restrict__ Xbf,
    const u16* __restrict__ WqT, const u16* __restrict__ WkT, const u16* __restrict__ WvT,
    u16* __restrict__ Qbf, u16* __restrict__ Kbf, u16* __restrict__ Vbf,
    int tg, int lsh)
{
  const int z = blockIdx.z;
  const u16* BT = (z == 0) ? WqT : ((z == 1) ? WkT : WvT);
  u16* O = (z == 0) ? Qbf : ((z == 1) ? Kbf : Vbf);
  const float scale = (z == 0) ? 0.03125f : 1.0f;
  const int r0 = blockIdx.x * 128, c0 = blockIdx.y * 128;
  const int tid = threadIdx.x;
  const int lane = tid & 63, wave = tid >> 6;
  const int quad = lane >> 4, l16 = lane & 15;
  const int wr = (wave >> 1) * 64, wc = (wave & 1) * 64;

  __shared__ u16 As[128 * 32];
  __shared__ u16 Bs[128 * 32];

  // Staging coords: wave covers 16 rows/round, lane l -> row l>>2, 16B seg l&3.
  const int srow = 16 * wave + (lane >> 2);
  const int scol = (lane & 3) * 8;
  const int lrA0 = r0 + srow, lrA1 = r0 + 64 + srow;
  const int gA0 = ((lrA0 >> lsh) << 11) + tg + (lrA0 & ((1 << lsh) - 1));
  const int gA1 = ((lrA1 >> lsh) << 11) + tg + (lrA1 & ((1 << lsh) - 1));
  const u16* pA0 = &Xbf[(size_t)gA0 * 1024 + scol];
  const u16* pA1 = &Xbf[(size_t)gA1 * 1024 + scol];
  const u16* pB0 = &BT[(size_t)(c0 + srow) * 1024 + scol];
  const u16* pB1 = &BT[(size_t)(c0 + 64 + srow) * 1024 + scol];
  u16* lA0 = &As[(16 * wave) * 32];        // wave-uniform LDS bases
  u16* lA1 = &As[(64 + 16 * wave) * 32];
  u16* lB0 = &Bs[(16 * wave) * 32];
  u16* lB1 = &Bs[(64 + 16 * wave) * 32];

  floatx4 acc[4][4] = {};
  for (int k0 = 0; k0 < 1024; k0 += 32) {
    __syncthreads();                       // prior tile's reads complete
    gll16(pA0 + k0, lA0);
    gll16(pA1 + k0, lA1);
    gll16(pB0 + k0, lB0);
    gll16(pB1 + k0, lB1);
    __syncthreads();                       // drains vmcnt: staged data visible
    short8 afr[4], bfr[4];
#pragma unroll
    for (int i = 0; i < 4; ++i) {
      afr[i] = *reinterpret_cast<const short8*>(&As[(wr + i * 16 + l16) * 32 + quad * 8]);
      bfr[i] = *reinterpret_cast<const short8*>(&Bs[(wc + i * 16 + l16) * 32 + quad * 8]);
    }
#pragma unroll
    for (int mi = 0; mi < 4; ++mi)
#pragma unroll
      for (int ni = 0; ni < 4; ++ni)
        acc[mi][ni] = __builtin_amdgcn_mfma_f32_16x16x32_bf16(afr[mi], bfr[ni], acc[mi][ni], 0, 0, 0);
  }
#pragma unroll
  for (int mi = 0; mi < 4; ++mi)
#pragma unroll
    for (int reg = 0; reg < 4; ++reg) {
      int row = r0 + wr + mi * 16 + quad * 4 + reg;
#pragma unroll
      for (int ni = 0; ni < 4; ++ni) {
        int col = c0 + wc + ni * 16 + l16;
        O[(size_t)row * 1024 + col] = f2bf(acc[mi][ni][reg] * scale);
      }
    }
}

// ---------------------------------------------------------------------------
// MFMA GEMM out-proj, m97-style staging (see mgemm_qkv). fp32 out.
// grid (rows/128, 8).
// ---------------------------------------------------------------------------
__global__ __launch_bounds__(256) void mgemm_out(
    const u16* __restrict__ Obf, const u16* __restrict__ WoT,
    float* __restrict__ out, int tg, int lsh)
{
  const int r0 = blockIdx.x * 128, c0 = blockIdx.y * 128;
  const int tid = threadIdx.x;
  const int lane = tid & 63, wave = tid >> 6;
  const int quad = lane >> 4, l16 = lane & 15;
  const int wr = (wave >> 1) * 64, wc = (wave & 1) * 64;

  __shared__ u16 As[128 * 32];
  __shared__ u16 Bs[128 * 32];

  const int srow = 16 * wave + (lane >> 2);
  const int scol = (lane & 3) * 8;
  const u16* pA0 = &Obf[(size_t)(r0 + srow) * 1024 + scol];
  const u16* pA1 = &Obf[(size_t)(r0 + 64 + srow) * 1024 + scol];
  const u16* pB0 = &WoT[(size_t)(c0 + srow) * 1024 + scol];
  const u16* pB1 = &WoT[(size_t)(c0 + 64 + srow) * 1024 + scol];
  u16* lA0 = &As[(16 * wave) * 32];
  u16* lA1 = &As[(64 + 16 * wave) * 32];
  u16* lB0 = &Bs[(16 * wave) * 32];
  u16* lB1 = &Bs[(64 + 16 * wave) * 32];

  floatx4 acc[4][4] = {};
  for (int k0 = 0; k0 < 1024; k0 += 32) {
    __syncthreads();
    gll16(pA0 + k0, lA0);
    gll16(pA1 + k0, lA1);
    gll16(pB0 + k0, lB0);
    gll16(pB1 + k0, lB1);
    __syncthreads();
    short8 afr[4], bfr[4];
#pragma unroll
    for (int i = 0; i < 4; ++i) {
      afr[i] = *reinterpret_cast<const short8*>(&As[(wr + i * 16 + l16) * 32 + quad * 8]);
      bfr[i] = *reinterpret_cast<const short8*>(&Bs[(wc + i * 16 + l16) * 32 + quad * 8]);
    }
#pragma unroll
    for (int mi = 0; mi < 4; ++mi)
#pragma unroll
      for (int ni = 0; ni < 4; ++ni)
        acc[mi][ni] = __builtin_amdgcn_mfma_f32_16x16x32_bf16(afr[mi], bfr[ni], acc[mi][ni], 0, 0, 0);
  }
#pragma unroll
  for (int mi = 0; mi < 4; ++mi)
#pragma unroll
    for (int reg = 0; reg < 4; ++reg) {
      int lr = r0 + wr + mi * 16 + quad * 4 + reg;
      int grow = ((lr >> lsh) << 11) + tg + (lr & ((1 << lsh) - 1));
#pragma unroll
      for (int ni = 0; ni < 4; ++ni) {
        int col = c0 + wc + ni * 16 + l16;
        out[(size_t)grow * 1024 + col] = acc[mi][ni][reg];
      }
    }
}

// ---------------------------------------------------------------------------
// Row-normalize Kbf in place (bf16, fp32 math). grid (rows).
// ---------------------------------------------------------------------------
__global__ __launch_bounds__(256) void knorm_kernel(u16* __restrict__ Kbf) {
  const int row = blockIdx.x;
  const int tid = threadIdx.x;
  ushort4 v4 = *reinterpret_cast<const ushort4*>(&Kbf[(size_t)row * 1024 + tid * 4]);
  float a = bf2f(v4.x), b = bf2f(v4.y), c = bf2f(v4.z), d = bf2f(v4.w);
  float ss = a * a + b * b + c * c + d * d;
#pragma unroll
  for (int off = 32; off > 0; off >>= 1) ss += __shfl_down(ss, off);
  __shared__ float wsum[4];
  if ((tid & 63) == 0) wsum[tid >> 6] = ss;
  __syncthreads();
  float tot = wsum[0] + wsum[1] + wsum[2] + wsum[3];
  float inv = 1.0f / fmaxf(sqrtf(tot), 1e-12f);
  ushort4 o;
  o.x = f2bf(a * inv); o.y = f2bf(b * inv); o.z = f2bf(c * inv); o.w = f2bf(d * inv);
  *reinterpret_cast<ushort4*>(&Kbf[(size_t)row * 1024 + tid * 4]) = o;
}

// ---------------------------------------------------------------------------
// Transpose Kbf -> KT[b][d][t_local] (bf16). grid (tgs/64, 16, B_), 256 thr.
// ---------------------------------------------------------------------------
__global__ __launch_bounds__(256) void ktrans_kernel(const u16* __restrict__ Kbf,
                                                     u16* __restrict__ KT,
                                                     int tgs) {
  const int t0 = blockIdx.x * 64;
  const int d0 = blockIdx.y * 64;
  const int b = blockIdx.z;
  const int tid = threadIdx.x;
  __shared__ u16 Tile[64][68];
#pragma unroll
  for (int i = 0; i < 4; ++i) {
    int lin = tid + i * 256;
    int r = lin >> 4, c4 = (lin & 15) * 4;
    *reinterpret_cast<ushort4*>(&Tile[r][c4]) =
        *reinterpret_cast<const ushort4*>(&Kbf[(size_t)(b * tgs + t0 + r) * 1024 + d0 + c4]);
  }
  __syncthreads();
#pragma unroll
  for (int i = 0; i < 4; ++i) {
    int lin = tid + i * 256;
    int r = lin >> 4, c4 = (lin & 15) * 4;
    ushort4 o;
    o.x = Tile[c4 + 0][r]; o.y = Tile[c4 + 1][r];
    o.z = Tile[c4 + 2][r]; o.w = Tile[c4 + 3][r];
    *reinterpret_cast<ushort4*>(&KT[((size_t)b * 1024 + d0 + r) * tgs + t0 + c4]) = o;
  }
}

// ---------------------------------------------------------------------------
// Per (chunk, batch): MFMA QK^T/KK^T -> P and A -> W=(I+A)^{-1} -> bf16.
// grid (cpg, B_), 256 threads.
// ---------------------------------------------------------------------------
__global__ __launch_bounds__(256) void attn_winv_kernel(
    const u16* __restrict__ Qbf, const u16* __restrict__ Kbf,
    u16* __restrict__ Pb, u16* __restrict__ Wb, int tgs)
{
  const int cc = blockIdx.x;
  const int b = blockIdx.y;
  const int base = b * tgs + cc * CH;
  const int tid = threadIdx.x;
  const int lane = tid & 63;
  const int wave = tid >> 6;
  const int quad = lane >> 4, l16 = lane & 15;
  const int m0 = wave * 16;

  __shared__ float Asm[64][64];
  __shared__ float Wsm[64][65];

  floatx4 accA[4] = {};
  floatx4 accP[4] = {};
  const u16* arowK = &Kbf[(size_t)(base + m0 + l16) * 1024];
  const u16* arowQ = &Qbf[(size_t)(base + m0 + l16) * 1024];
#pragma unroll 4
  for (int kk = 0; kk < 32; ++kk) {
    short8 aK = *reinterpret_cast<const short8*>(&arowK[kk * 32 + quad * 8]);
    short8 aQ = *reinterpret_cast<const short8*>(&arowQ[kk * 32 + quad * 8]);
#pragma unroll
    for (int nt = 0; nt < 4; ++nt) {
      short8 bK = *reinterpret_cast<const short8*>(
          &Kbf[(size_t)(base + nt * 16 + l16) * 1024 + kk * 32 + quad * 8]);
      accA[nt] = __builtin_amdgcn_mfma_f32_16x16x32_bf16(aK, bK, accA[nt], 0, 0, 0);
      accP[nt] = __builtin_amdgcn_mfma_f32_16x16x32_bf16(aQ, bK, accP[nt], 0, 0, 0);
    }
  }
  const size_t pw0 = ((size_t)(cc * B_ + b) * CH) * 64;
#pragma unroll
  for (int nt = 0; nt < 4; ++nt) {
#pragma unroll
    for (int reg = 0; reg < 4; ++reg) {
      int t = m0 + quad * 4 + reg;
      int i = nt * 16 + l16;
      Asm[t][i] = (i < t) ? accA[nt][reg] : 0.0f;
      Pb[pw0 + (size_t)t * 64 + i] = f2bf((i <= t) ? accP[nt][reg] : 0.0f);
    }
  }
  __syncthreads();

  if (tid < 64) {
    const int j = tid;
    for (int t = 0; t < 64; ++t) {
      float s = (t == j) ? 1.0f : 0.0f;
      for (int i = 0; i < t; ++i) s -= Asm[t][i] * Wsm[i][j];
      Wsm[t][j] = s;
    }
    for (int t = 0; t < 64; ++t)
      Wb[pw0 + (size_t)t * 64 + j] = f2bf(Wsm[t][j]);
  }
}

// ---------------------------------------------------------------------------
// Persistent-state MFMA chain, v7 (UNCHANGED this round; parked at ~380us).
// 7 structural variants (v1-v7) all land ~380-430 with MfmaUtil ~5.5% ->
// intrinsic per-chunk serial-latency floor at 1 WG/CU (grid=256 is the
// parallelism limit). This round's lever is the projection GEMMs instead.
// Ledger (both roles): entry 30 = [af0,af1,ktf16,wpf2,vv4];
//   A_IT waits: 26,26,4,4,4,4,4,4; ktf' after C; wpf'/vv' after o.
// ---------------------------------------------------------------------------
__global__ __launch_bounds__(512, 2) void chain_kernel(
    const u16* __restrict__ Qbf, const u16* __restrict__ Kbf,
    const u16* __restrict__ KT, const u16* __restrict__ Vbf,
    u16* __restrict__ Obf, const u16* __restrict__ Wb, const u16* __restrict__ Pb,
    float* __restrict__ Sglob, int lsh, int cpg, int g, int ngrp)
{
  const int wg = blockIdx.x;
  // XCD pair {2b, 2b+1} hosts exactly batch b's 64 slices (bijective).
  const int t8 = wg & 7;
  const int b = t8 >> 1;
  const int sl = ((wg >> 3) << 1) | (t8 & 1);
  const int c0 = sl * 16;
  const int tgs = 1 << lsh;
  const int tid = threadIdx.x;
  const int lane = tid & 63;
  const int wave = tid >> 6;
  const int quad = lane >> 4, l16 = lane & 15;
  const int d0w = wave * 128;
  const bool isK = (wave < 4);
  const int m0 = (isK ? wave : (wave - 4)) * 16;
  const size_t ktstep = (size_t)16 * tgs;

  __shared__ u16 Sb[16][1048];   // bf16 shadow (524 words/row = 12 mod 32)
  __shared__ u16 rhsT[16][88];   // (V - KS)^T bf16
  __shared__ u16 uT[16][88];     // u^T bf16

  // fp32 master S: Sreg[nt][reg] <-> S[c=quad*4+reg][d=d0w+nt*16+l16]
  floatx4 Sreg[8];
  if (g == 0) {
#pragma unroll
    for (int nt = 0; nt < 8; ++nt) Sreg[nt] = (floatx4){0.f, 0.f, 0.f, 0.f};
    for (int idx = tid; idx < 16 * 256; idx += 512) {
      int r = idx >> 8, d4 = (idx & 255) * 4;
      ushort4 z4 = {0, 0, 0, 0};
      *reinterpret_cast<ushort4*>(&Sb[r][d4]) = z4;
    }
  } else {
#pragma unroll
    for (int nt = 0; nt < 8; ++nt)
#pragma unroll
      for (int reg = 0; reg < 4; ++reg)
        Sreg[nt][reg] = Sglob[((size_t)b * 1024 + c0 + quad * 4 + reg) * 1024 +
                              d0w + nt * 16 + l16];
    for (int idx = tid; idx < 16 * 1024; idx += 512) {
      int r = idx >> 10, d = idx & 1023;
      Sb[r][d] = f2bf(Sglob[((size_t)b * 1024 + c0 + r) * 1024 + d]);
    }
  }
  __syncthreads();   // drains vmcnt: ledger starts at 0

  const u16* const Abase = isK ? Kbf : Qbf;
  const u16* const WPbase = isK ? Wb : Pb;

  short8 af[8][4];    // A-frag ring; slot k holds iter-k frags
  short8 ktf[8][2];
  short8 wpf0, wpf1;
  unsigned int vv0, vv1, vv2, vv3;

  const u16* arow = Abase + (size_t)(b * tgs + m0 + l16) * 1024;  // chunk 0

  // Prologue (chunk 0), issue order MUST match steady entry:
  // af0, af1, ktf16, wpf2, vv4  -> 30 outstanding.
  {
    const u16* aq0 = arow + quad * 8;
    GLA(0, aq0, 0, 64, 128, 192);
    GLA(1, aq0, 256, 320, 384, 448);
    const u16* ktbn = KT + ((size_t)b * 1024 + d0w + l16) * tgs + quad * 8;
    GLKT(0); GLKT(2); GLKT(4); GLKT(6);
    const u16* wrow0 = WPbase + (size_t)(b * CH * 0 + 0) + ((size_t)(0 * B_ + b) * CH) * 64 +
                       (size_t)(m0 + l16) * 64 + quad * 8;
    GL(wpf0, wrow0, 0); GL(wpf1, wrow0, 64);
    const u16* vvb0  = Vbf + (size_t)(b * tgs + m0 + quad * 4) * 1024 + c0 + l16;
    const u16* vvb02 = vvb0 + 2048;
    GLU(vv0, vvb0, 0); GLU(vv1, vvb0, 2048);
    GLU(vv2, vvb02, 0); GLU(vv3, vvb02, 2048);
  }

  for (int cc = 0; cc < cpg; ++cc) {
    const int base = b * tgs + cc * CH;
    const int nx = (cc + 1 < cpg) ? (cc + 1) : (cpg - 1);

    const u16* aq  = arow + quad * 8;
    const u16* aqn = arow + (size_t)(cc + 1 < cpg ? CH * 1024 : 0) + quad * 8;

    floatx4 ac0 = {}, ac1 = {}, ac2 = {}, ac3 = {};

    // ---- phase A: af-only issue (depth-2 ring); waits retire the older
    //      ktf/wpf/vv(cc) groups implicitly (issued last chunk, done). ----
    A_IT(0, 26, GLA(2, aq, 512, 576, 640, 704));
    A_IT(1, 26, GLA(3, aq, 768, 832, 896, 960));
    A_IT(2, 4,  GLA(4, aq, 1024, 1088, 1152, 1216));
    A_IT(3, 4,  GLA(5, aq, 1280, 1344, 1408, 1472));
    A_IT(4, 4,  GLA(6, aq, 1536, 1600, 1664, 1728));
    A_IT(5, 4,  GLA(7, aq, 1792, 1856, 1920, 1984));
    A_IT(6, 4,  GLA(0, aqn, 0, 64, 128, 192));
    A_IT(7, 4,  GLA(1, aqn, 256, 320, 384, 448));

    floatx4 accS = (ac0 + ac1) + (ac2 + ac3);

    // ---- rhs = V - KS (K-waves); vv retired at A_IT2's wait(4) ----
    if (isK) {
      rhsT[l16][m0 + quad * 4 + 0] = f2bf(bf2f((u16)vv0) - accS[0]);
      rhsT[l16][m0 + quad * 4 + 1] = f2bf(bf2f((u16)vv1) - accS[1]);
      rhsT[l16][m0 + quad * 4 + 2] = f2bf(bf2f((u16)vv2) - accS[2]);
      rhsT[l16][m0 + quad * 4 + 3] = f2bf(bf2f((u16)vv3) - accS[3]);
    }
    barrier_lgkm();

    // ---- u = W * rhs (K-waves) ----
    if (isK) {
      floatx4 uacc = {};
      short8 br0 = *reinterpret_cast<const short8*>(&rhsT[l16][quad * 8]);
      short8 br1 = *reinterpret_cast<const short8*>(&rhsT[l16][32 + quad * 8]);
      uacc = __builtin_amdgcn_mfma_f32_16x16x32_bf16(wpf0, br0, uacc, 0, 0, 0);
      uacc = __builtin_amdgcn_mfma_f32_16x16x32_bf16(wpf1, br1, uacc, 0, 0, 0);
#pragma unroll
      for (int reg = 0; reg < 4; ++reg)
        uT[l16][m0 + quad * 4 + reg] = f2bf(uacc[reg]);
    }
    barrier_lgkm();

    short8 ua0 = *reinterpret_cast<const short8*>(&uT[l16][quad * 8]);
    short8 ua1 = *reinterpret_cast<const short8*>(&uT[l16][32 + quad * 8]);

    // ---- phase C: Sreg += u^T K (consumes ktf(cc)) ----
    {
#pragma unroll
      for (int nt = 0; nt < 8; ++nt) {
        floatx4 cf = Sreg[nt];
        cf = __builtin_amdgcn_mfma_f32_16x16x32_bf16(ua0, ktf[nt][0], cf, 0, 0, 0);
        cf = __builtin_amdgcn_mfma_f32_16x16x32_bf16(ua1, ktf[nt][1], cf, 0, 0, 0);
        Sreg[nt] = cf;
        const int dn = d0w + nt * 16;
#pragma unroll
        for (int reg = 0; reg < 4; ++reg)
          Sb[quad * 4 + reg][dn + l16] = f2bf(cf[reg]);
      }
    }

    // ---- issue ktf(cc+1): fills the TA pipe during the C/o window ----
    {
      const u16* ktbn = KT + ((size_t)b * 1024 + d0w + l16) * tgs +
                        (size_t)nx * CH + quad * 8;
      GLKT(0); GLKT(2); GLKT(4); GLKT(6);
    }

    // ---- o = QS + P*u (Q-waves, reads wpf(cc) BEFORE wpf' issue) ----
    if (!isK) {
      floatx4 oacc = accS;
      oacc = __builtin_amdgcn_mfma_f32_16x16x32_bf16(wpf0, ua0, oacc, 0, 0, 0);
      oacc = __builtin_amdgcn_mfma_f32_16x16x32_bf16(wpf1, ua1, oacc, 0, 0, 0);
      u16* ob  = Obf + (size_t)(base + m0 + quad * 4) * 1024 + c0 + l16;
      u16* ob2 = ob + 2048;
      unsigned int s0 = f2bf(oacc[0]), s1 = f2bf(oacc[1]);
      unsigned int s2 = f2bf(oacc[2]), s3 = f2bf(oacc[3]);
      GS(ob, s0, 0);  GS(ob, s1, 2048);
      GS(ob2, s2, 0); GS(ob2, s3, 2048);
    }

    // ---- issue wpf(cc+1), vv(cc+1) ----
    {
      const size_t pwN = ((size_t)(nx * B_ + b) * CH) * 64;
      const u16* wrow = WPbase + pwN + (size_t)(m0 + l16) * 64 + quad * 8;
      GL(wpf0, wrow, 0); GL(wpf1, wrow, 64);
      const u16* vvb  = Vbf + (size_t)(b * tgs + nx * CH + m0 + quad * 4) * 1024 + c0 + l16;
      const u16* vvb2 = vvb + 2048;
      GLU(vv0, vvb, 0); GLU(vv1, vvb, 2048);
      GLU(vv2, vvb2, 0); GLU(vv3, vvb2, 2048);
    }

    barrier_lgkm();
    arow += CH * 1024;
  }

  asm volatile("s_waitcnt vmcnt(0)");   // retire in-flight asm loads/stores

  // spill S for next group (small-ws tiers only; full tier has ngrp==1)
  if (g < ngrp - 1) {
#pragma unroll
    for (int nt = 0; nt < 8; ++nt)
#pragma unroll
      for (int reg = 0; reg < 4; ++reg)
        Sglob[((size_t)b * 1024 + c0 + quad * 4 + reg) * 1024 + d0w + nt * 16 + l16] =
            Sreg[nt][reg];
  }
}

// ---------------------------------------------------------------------------
extern "C" void kernel_launch(void* const* d_in, const int* in_sizes, int n_in,
                              void* d_out, int out_size, void* d_ws, size_t ws_size,
                              hipStream_t stream) {
  const float* x  = (const float*)d_in[0];
  const float* Wq = (const float*)d_in[1];
  const float* Wk = (const float*)d_in[2];
  const float* Wv = (const float*)d_in[3];
  const float* Wo = (const float*)d_in[4];
  float* out = (float*)d_out;

  // tier: largest time-group that fits ws
  int lsh = 8;
  {
    const int cand[4] = {11, 10, 9, 8};
    for (int i = 0; i < 4; ++i) {
      size_t tgs = (size_t)1 << cand[i];
      size_t C = (size_t)B_ * tgs * 1024;
      size_t cpg = tgs / CH;
      size_t need = (size_t)B_ * T_ * 1024 * 2              // Xbf
                  + 4 * ((size_t)1024 * 1024 * 2)           // WT x4
                  + 5 * (C * 2)                             // Qbf,Kbf,Vbf,KT,Obf
                  + 2 * (cpg * B_ * CH * 64 * 2)            // Pb,Wb
                  + (size_t)B_ * 1024 * 1024 * 4            // Sglob
                  + 32768;
      if (need <= ws_size) { lsh = cand[i]; break; }
    }
  }
  const int tgs = 1 << lsh;
  const int cpg = tgs / CH;
  const int ngrp = T_ / tgs;
  const int rows = B_ * tgs;

  char* ws = (char*)d_ws;
  size_t off = 0;
  auto alloc = [&](size_t bytes) -> void* {
    void* p = ws + off;
    off += (bytes + 255) & ~(size_t)255;
    return p;
  };
  u16* Xbf = (u16*)alloc((size_t)B_ * T_ * 1024 * 2);
  u16* WqT = (u16*)alloc((size_t)1024 * 1024 * 2);
  u16* WkT = (u16*)alloc((size_t)1024 * 1024 * 2);
  u16* WvT = (u16*)alloc((size_t)1024 * 1024 * 2);
  u16* WoT = (u16*)alloc((size_t)1024 * 1024 * 2);
  u16* Qbf = (u16*)alloc((size_t)rows * 1024 * 2);
  u16* Kbf = (u16*)alloc((size_t)rows * 1024 * 2);
  u16* Vbf = (u16*)alloc((size_t)rows * 1024 * 2);
  u16* KT  = (u16*)alloc((size_t)rows * 1024 * 2);
  u16* Obf = (u16*)alloc((size_t)rows * 1024 * 2);
  u16* Pb  = (u16*)alloc((size_t)cpg * B_ * CH * 64 * 2);
  u16* Wb  = (u16*)alloc((size_t)cpg * B_ * CH * 64 * 2);
  float* Sglob = (float*)alloc((size_t)B_ * 1024 * 1024 * 4);

  xconv_kernel<<<B_ * T_, 256, 0, stream>>>(x, Xbf);
  wtrans_kernel<<<dim3(16, 16, 4), 256, 0, stream>>>(Wq, Wk, Wv, Wo, WqT, WkT, WvT, WoT);

  for (int g = 0; g < ngrp; ++g) {
    int tg = g * tgs;
    mgemm_qkv<<<dim3(rows / 128, 8, 3), 256, 0, stream>>>(Xbf, WqT, WkT, WvT,
                                                          Qbf, Kbf, Vbf, tg, lsh);
    knorm_kernel<<<rows, 256, 0, stream>>>(Kbf);
    ktrans_kernel<<<dim3(tgs / 64, 16, B_), 256, 0, stream>>>(Kbf, KT, tgs);
    attn_winv_kernel<<<dim3(cpg, B_), 256, 0, stream>>>(Qbf, Kbf, Pb, Wb, tgs);
    chain_kernel<<<256, 512, 0, stream>>>(Qbf, Kbf, KT, Vbf, Obf, Wb, Pb, Sglob,
                                          lsh, cpg, g, ngrp);
    mgemm_out<<<dim3(rows / 128, 8), 256, 0, stream>>>(Obf, WoT, out, tg, lsh);
  }
}